// Round 1
// baseline (945.820 us; speedup 1.0000x reference)
//
#include <hip/hip_runtime.h>
#include <hip/hip_bf16.h>
#include <math.h>

#define LSEQ 4096
#define NR   16384   // B*L
#define NB   4

__device__ __forceinline__ float softplus_f(float x) {
    return x > 20.f ? x : log1pf(__expf(x));
}

// ---------------- Kernel 1: per-row mean / rstd ----------------
__global__ __launch_bounds__(256) void rowstats_kernel(const float* __restrict__ in1,
                                                       const float* __restrict__ in2,
                                                       float* __restrict__ mu,
                                                       float* __restrict__ rs) {
    __shared__ float s1[4][64], s2[4][64];
    int tt = threadIdx.x & 63, cc = threadIdx.x >> 6;
    int blk = blockIdx.x;            // NB * 64
    int b = blk >> 6;
    int t = ((blk & 63) << 6) + tt;
    float a1 = 0.f, a2 = 0.f;
    for (int i = 0; i < 64; ++i) {
        int c = cc * 64 + i;
        float v = (c < 128) ? in1[(size_t)((b << 7) + c) * LSEQ + t]
                            : in2[(size_t)((b << 7) + (c - 128)) * LSEQ + t];
        a1 += v; a2 += v * v;
    }
    s1[cc][tt] = a1; s2[cc][tt] = a2;
    __syncthreads();
    if (cc == 0) {
        float t1 = s1[0][tt] + s1[1][tt] + s1[2][tt] + s1[3][tt];
        float t2 = s2[0][tt] + s2[1][tt] + s2[2][tt] + s2[3][tt];
        float m = t1 * (1.f / 256.f);
        float var = t2 * (1.f / 256.f) - m * m;
        int r = (b << 12) + t;
        mu[r] = m;
        rs[r] = rsqrtf(var + 1e-5f);
    }
}

// ---------------- Kernel 2: combined weight Wc = Wm(512x256) @ Wo(256x128) ----------------
__global__ __launch_bounds__(256) void wc_kernel(const float* __restrict__ Wm,
                                                 const float* __restrict__ Wo,
                                                 float* __restrict__ Wc) {
    int gid = blockIdx.x * 256 + threadIdx.x;   // 65536
    int row = gid >> 7, col = gid & 127;
    float acc = 0.f;
    for (int k = 0; k < 256; ++k) acc += Wm[row * 256 + k] * Wo[k * 128 + col];
    Wc[gid] = acc;
}

// ---------------- Kernel 3: fused LN + in_proj GEMM ----------------
// xz[r, n] = LN(x[r, :]) @ W[:, n],  M=16384 N=1024 K=256
// 128x64 tile, 8x4 microtile, BK=16
__global__ __launch_bounds__(256) void gemm1_ln(const float* __restrict__ in1,
                                                const float* __restrict__ in2,
                                                const float* __restrict__ mu,
                                                const float* __restrict__ rs,
                                                const float* __restrict__ g,
                                                const float* __restrict__ beta,
                                                const float* __restrict__ W,
                                                float* __restrict__ xz) {
    __shared__ float As[16][132];
    __shared__ float Bs[16][64];
    __shared__ float smu[128], srs[128], sg[256], sbt[256];
    int tid = threadIdx.x;
    int r0 = blockIdx.x * 128;
    int b  = r0 >> 12;
    int t0 = r0 & 4095;
    int n0 = blockIdx.y * 64;
    int tx = tid & 15, ty = tid >> 4;

    if (tid < 128) { smu[tid] = mu[r0 + tid]; srs[tid] = rs[r0 + tid]; }
    sg[tid] = g[tid & 255]; sbt[tid] = beta[tid & 255];
    if (tid < 256) { }  // (256 threads cover 256 entries exactly)
    __syncthreads();

    float acc[8][4];
    #pragma unroll
    for (int i = 0; i < 8; ++i)
        #pragma unroll
        for (int j = 0; j < 4; ++j) acc[i][j] = 0.f;

    for (int k0 = 0; k0 < 256; k0 += 16) {
        #pragma unroll
        for (int i = 0; i < 8; ++i) {
            int e = tid + i * 256;
            int m = e & 127, kk = e >> 7;
            int c = k0 + kk;
            int t = t0 + m;
            float raw = (c < 128) ? in1[(size_t)((b << 7) + c) * LSEQ + t]
                                  : in2[(size_t)((b << 7) + (c - 128)) * LSEQ + t];
            As[kk][m] = (raw - smu[m]) * srs[m] * sg[c] + sbt[c];
        }
        #pragma unroll
        for (int i = 0; i < 4; ++i) {
            int e = tid + i * 256;
            int n = e & 63, kk = e >> 6;
            Bs[kk][n] = W[(size_t)(k0 + kk) * 1024 + n0 + n];
        }
        __syncthreads();
        #pragma unroll
        for (int kk = 0; kk < 16; ++kk) {
            float4 a0 = *(const float4*)&As[kk][ty * 8];
            float4 a1 = *(const float4*)&As[kk][ty * 8 + 4];
            float4 bv = *(const float4*)&Bs[kk][tx * 4];
            float av[8] = {a0.x, a0.y, a0.z, a0.w, a1.x, a1.y, a1.z, a1.w};
            float bb[4] = {bv.x, bv.y, bv.z, bv.w};
            #pragma unroll
            for (int im = 0; im < 8; ++im)
                #pragma unroll
                for (int jn = 0; jn < 4; ++jn) acc[im][jn] += av[im] * bb[jn];
        }
        __syncthreads();
    }
    #pragma unroll
    for (int im = 0; im < 8; ++im) {
        int r = r0 + ty * 8 + im;
        float4 v = make_float4(acc[im][0], acc[im][1], acc[im][2], acc[im][3]);
        *(float4*)&xz[(size_t)r * 1024 + n0 + tx * 4] = v;
    }
}

// ---------------- Kernel 4: causal depthwise conv(k=4) + SiLU ----------------
__global__ __launch_bounds__(256) void conv_kernel(const float* __restrict__ xz,
                                                   const float* __restrict__ cw,
                                                   const float* __restrict__ cb,
                                                   float* __restrict__ xc) {
    int r = blockIdx.x;
    int b = r >> 12, t = r & 4095;
    #pragma unroll
    for (int i = 0; i < 2; ++i) {
        int d = threadIdx.x + i * 256;
        float acc = cb[d];
        #pragma unroll
        for (int k = 0; k < 4; ++k) {
            int tt = t - 3 + k;
            if (tt >= 0) acc += xz[(size_t)((b << 12) + tt) * 1024 + d] * cw[d * 4 + k];
        }
        xc[(size_t)r * 512 + d] = acc / (1.f + __expf(-acc));   // silu
    }
}

// ---------------- Kernel 5: x_proj GEMM  M=16384 N=48 K=512 ----------------
// 64-row tile, microtile 4x3, BK=32
__global__ __launch_bounds__(256) void xproj_gemm(const float* __restrict__ xc,
                                                  const float* __restrict__ Wxp,
                                                  float* __restrict__ xdbl) {
    __shared__ float Xs[32][65];
    __shared__ float Ws[32][49];
    int tid = threadIdx.x;
    int r0 = blockIdx.x * 64;
    int tx = tid & 15, ty = tid >> 4;
    float acc[4][3];
    #pragma unroll
    for (int i = 0; i < 4; ++i)
        #pragma unroll
        for (int j = 0; j < 3; ++j) acc[i][j] = 0.f;

    for (int k0 = 0; k0 < 512; k0 += 32) {
        #pragma unroll
        for (int i = 0; i < 8; ++i) {
            int e = tid + i * 256;
            int kk = e & 31, m = e >> 5;
            Xs[kk][m] = xc[(size_t)(r0 + m) * 512 + k0 + kk];
        }
        #pragma unroll
        for (int i = 0; i < 6; ++i) {
            int e = tid + i * 256;
            int kk = e / 48, j = e - kk * 48;
            Ws[kk][j] = Wxp[(size_t)(k0 + kk) * 48 + j];
        }
        __syncthreads();
        #pragma unroll
        for (int kk = 0; kk < 32; ++kk) {
            float a[4], w[3];
            #pragma unroll
            for (int i = 0; i < 4; ++i) a[i] = Xs[kk][ty * 4 + i];
            #pragma unroll
            for (int j = 0; j < 3; ++j) w[j] = Ws[kk][tx * 3 + j];
            #pragma unroll
            for (int i = 0; i < 4; ++i)
                #pragma unroll
                for (int j = 0; j < 3; ++j) acc[i][j] += a[i] * w[j];
        }
        __syncthreads();
    }
    #pragma unroll
    for (int i = 0; i < 4; ++i)
        #pragma unroll
        for (int j = 0; j < 3; ++j)
            xdbl[(size_t)(r0 + ty * 4 + i) * 48 + tx * 3 + j] = acc[i][j];
}

// ---------------- Kernel 6: delta = softplus(dt @ Wdt + b), 4 rows/block ----------------
__global__ __launch_bounds__(256) void dt_kernel(const float* __restrict__ xdbl,
                                                 const float* __restrict__ Wdt,
                                                 const float* __restrict__ dtb,
                                                 float* __restrict__ delta) {
    __shared__ float sdt[4][16];
    int r0 = blockIdx.x * 4;
    int tid = threadIdx.x;
    if (tid < 64) sdt[tid >> 4][tid & 15] = xdbl[(size_t)(r0 + (tid >> 4)) * 48 + (tid & 15)];
    __syncthreads();
    #pragma unroll
    for (int i = 0; i < 2; ++i) {
        int d = tid + i * 256;
        float bv = dtb[d];
        float a0 = bv, a1 = bv, a2 = bv, a3 = bv;
        #pragma unroll
        for (int q = 0; q < 16; ++q) {
            float w = Wdt[q * 512 + d];
            a0 += sdt[0][q] * w; a1 += sdt[1][q] * w;
            a2 += sdt[2][q] * w; a3 += sdt[3][q] * w;
        }
        delta[(size_t)(r0 + 0) * 512 + d] = softplus_f(a0);
        delta[(size_t)(r0 + 1) * 512 + d] = softplus_f(a1);
        delta[(size_t)(r0 + 2) * 512 + d] = softplus_f(a2);
        delta[(size_t)(r0 + 3) * 512 + d] = softplus_f(a3);
    }
}

// ---------------- Kernel 7: selective scan + gating ----------------
// block = (16 channels) x (16 states); 128 blocks = B * 32 channel-slices
// L chunked by 32, LDS-staged with register prefetch of next chunk.
__global__ __launch_bounds__(256) void scan_kernel(const float* __restrict__ delta,
                                                   const float* __restrict__ xc,
                                                   const float* __restrict__ xz,
                                                   const float* __restrict__ xdbl,
                                                   const float* __restrict__ A_log,
                                                   const float* __restrict__ Dp,
                                                   float* __restrict__ yf) {
    __shared__ float sd[32][16], sx[32][16], sz[32][16], sB[32][16], sC[32][16];
    __shared__ float sy[32][16][17];
    int tid = threadIdx.x;
    int n = tid & 15, dl = tid >> 4;
    int b = blockIdx.x >> 5;
    int d0 = (blockIdx.x & 31) << 4;
    int d = d0 + dl;
    float Aneg = -__expf(A_log[d * 16 + n]);
    float Dv = Dp[d];

    int tl0 = tid >> 4, j0 = tid & 15;   // element 0: rows 0..15
    int tl1 = tl0 + 16, j1 = j0;         // element 1: rows 16..31

    float rd0, rd1, rx0, rx1, rz0, rz1, rB0, rB1, rC0, rC1;
    {
        size_t r0 = (size_t)((b << 12) + tl0);
        size_t r1 = (size_t)((b << 12) + tl1);
        rd0 = delta[r0 * 512 + d0 + j0]; rd1 = delta[r1 * 512 + d0 + j1];
        rx0 = xc[r0 * 512 + d0 + j0];    rx1 = xc[r1 * 512 + d0 + j1];
        rz0 = xz[r0 * 1024 + 512 + d0 + j0]; rz1 = xz[r1 * 1024 + 512 + d0 + j1];
        rB0 = xdbl[r0 * 48 + 16 + j0];   rB1 = xdbl[r1 * 48 + 16 + j1];
        rC0 = xdbl[r0 * 48 + 32 + j0];   rC1 = xdbl[r1 * 48 + 32 + j1];
    }
    float h = 0.f;
    for (int c = 0; c < 128; ++c) {
        sd[tl0][j0] = rd0; sd[tl1][j1] = rd1;
        sx[tl0][j0] = rx0; sx[tl1][j1] = rx1;
        sz[tl0][j0] = rz0; sz[tl1][j1] = rz1;
        sB[tl0][j0] = rB0; sB[tl1][j1] = rB1;
        sC[tl0][j0] = rC0; sC[tl1][j1] = rC1;
        __syncthreads();
        if (c + 1 < 128) {
            int base = (b << 12) + (c + 1) * 32;
            size_t r0 = (size_t)(base + tl0), r1 = (size_t)(base + tl1);
            rd0 = delta[r0 * 512 + d0 + j0]; rd1 = delta[r1 * 512 + d0 + j1];
            rx0 = xc[r0 * 512 + d0 + j0];    rx1 = xc[r1 * 512 + d0 + j1];
            rz0 = xz[r0 * 1024 + 512 + d0 + j0]; rz1 = xz[r1 * 1024 + 512 + d0 + j1];
            rB0 = xdbl[r0 * 48 + 16 + j0];   rB1 = xdbl[r1 * 48 + 16 + j1];
            rC0 = xdbl[r0 * 48 + 32 + j0];   rC1 = xdbl[r1 * 48 + 32 + j1];
        }
        #pragma unroll 8
        for (int t = 0; t < 32; ++t) {
            float dv = sd[t][dl];
            float xv = sx[t][dl];
            float a = __expf(dv * Aneg);
            h = h * a + dv * xv * sB[t][n];
            float p = h * sC[t][n];
            if (n == 0) {
                p += xv * Dv;
                float zv = sz[t][dl];
                sy[t][dl][16] = zv / (1.f + __expf(-zv));   // silu(z)
            }
            sy[t][dl][n] = p;
        }
        __syncthreads();
        int rbase = (b << 12) + c * 32;
        #pragma unroll
        for (int i = 0; i < 2; ++i) {
            int e = tid + i * 256;
            int t = e >> 4, dli = e & 15;
            float acc = 0.f;
            #pragma unroll
            for (int q = 0; q < 16; ++q) acc += sy[t][dli][q];
            yf[(size_t)(rbase + t) * 512 + d0 + dli] = acc * sy[t][dli][16];
        }
    }
}

// ---------------- Kernel 8: final GEMM  out = yf @ Wc + bo, transposed store ----------------
// M=16384(t) x N=128(c), K=512;  tile 64x64, micro 4x4
__global__ __launch_bounds__(256) void gemm_out(const float* __restrict__ yf,
                                                const float* __restrict__ Wc,
                                                const float* __restrict__ bo,
                                                float* __restrict__ out) {
    __shared__ float As[16][68];
    __shared__ float Bs[16][64];
    int tid = threadIdx.x;
    int r0 = blockIdx.x * 64;
    int c0 = blockIdx.y * 64;
    int b = r0 >> 12, t0 = r0 & 4095;
    int tx = tid & 15, ty = tid >> 4;
    float acc[4][4];
    #pragma unroll
    for (int i = 0; i < 4; ++i)
        #pragma unroll
        for (int j = 0; j < 4; ++j) acc[i][j] = 0.f;

    for (int k0 = 0; k0 < 512; k0 += 16) {
        #pragma unroll
        for (int i = 0; i < 4; ++i) {
            int e = tid + i * 256;
            int kk = e & 15, tl = e >> 4;
            As[kk][tl] = yf[(size_t)(r0 + tl) * 512 + k0 + kk];
        }
        #pragma unroll
        for (int i = 0; i < 4; ++i) {
            int e = tid + i * 256;
            int cc = e & 63, kk = e >> 6;
            Bs[kk][cc] = Wc[(size_t)(k0 + kk) * 128 + c0 + cc];
        }
        __syncthreads();
        #pragma unroll
        for (int kk = 0; kk < 16; ++kk) {
            float4 av = *(const float4*)&As[kk][tx * 4];
            float4 bv = *(const float4*)&Bs[kk][ty * 4];
            float aa[4] = {av.x, av.y, av.z, av.w};
            float bb[4] = {bv.x, bv.y, bv.z, bv.w};
            #pragma unroll
            for (int ci = 0; ci < 4; ++ci)
                #pragma unroll
                for (int tj = 0; tj < 4; ++tj) acc[ci][tj] += bb[ci] * aa[tj];
        }
        __syncthreads();
    }
    #pragma unroll
    for (int ci = 0; ci < 4; ++ci) {
        int c = c0 + ty * 4 + ci;
        float bias = bo[c];
        float4 v = make_float4(acc[ci][0] + bias, acc[ci][1] + bias,
                               acc[ci][2] + bias, acc[ci][3] + bias);
        *(float4*)&out[((size_t)b * 128 + c) * LSEQ + t0 + tx * 4] = v;
    }
}

// ---------------- launch ----------------
extern "C" void kernel_launch(void* const* d_in, const int* in_sizes, int n_in,
                              void* d_out, int out_size, void* d_ws, size_t ws_size,
                              hipStream_t stream) {
    (void)in_sizes; (void)n_in; (void)out_size; (void)ws_size;
    const float* input    = (const float*)d_in[0];
    const float* input2   = (const float*)d_in[1];
    const float* ln_g     = (const float*)d_in[2];
    const float* ln_b     = (const float*)d_in[3];
    const float* outp_w   = (const float*)d_in[4];
    const float* outp_b   = (const float*)d_in[5];
    const float* in_proj  = (const float*)d_in[6];
    const float* conv_w   = (const float*)d_in[7];
    const float* conv_b   = (const float*)d_in[8];
    const float* x_proj   = (const float*)d_in[9];
    const float* dt_w     = (const float*)d_in[10];
    const float* dt_b     = (const float*)d_in[11];
    const float* A_log    = (const float*)d_in[12];
    const float* D_param  = (const float*)d_in[13];
    const float* mout_w   = (const float*)d_in[14];
    float* out = (float*)d_out;

    float* ws = (float*)d_ws;
    float* mu    = ws;                       // 16384
    float* rs    = mu + 16384;               // 16384
    float* xz    = rs + 16384;               // 16384*1024
    float* xc    = xz + (size_t)NR * 1024;   // 16384*512
    float* xdbl  = xc + (size_t)NR * 512;    // 16384*48
    float* delta = xdbl + (size_t)NR * 48;   // 16384*512
    float* yf    = delta + (size_t)NR * 512; // 16384*512
    float* Wc    = yf + (size_t)NR * 512;    // 512*128

    rowstats_kernel<<<NB * 64, 256, 0, stream>>>(input, input2, mu, rs);
    wc_kernel<<<256, 256, 0, stream>>>(mout_w, outp_w, Wc);
    gemm1_ln<<<dim3(NR / 128, 16), 256, 0, stream>>>(input, input2, mu, rs, ln_g, ln_b,
                                                     in_proj, xz);
    conv_kernel<<<NR, 256, 0, stream>>>(xz, conv_w, conv_b, xc);
    xproj_gemm<<<NR / 64, 256, 0, stream>>>(xc, x_proj, xdbl);
    dt_kernel<<<NR / 4, 256, 0, stream>>>(xdbl, dt_w, dt_b, delta);
    scan_kernel<<<NB * 32, 256, 0, stream>>>(delta, xc, xz, xdbl, A_log, D_param, yf);
    gemm_out<<<dim3(NR / 64, 2), 256, 0, stream>>>(yf, Wc, outp_b, out);
}

// Round 2
// 465.973 us; speedup vs baseline: 2.0298x; 2.0298x over previous
//
#include <hip/hip_runtime.h>
#include <hip/hip_bf16.h>
#include <math.h>

#define LSEQ 4096
#define NR   16384   // B*L
#define NB   4
#define CHUNK 64     // scan chunk length
#define NCH  64      // chunks per sequence (CHUNK*NCH == LSEQ)

__device__ __forceinline__ float softplus_f(float x) {
    return x > 20.f ? x : log1pf(__expf(x));
}

// ---------------- Kernel 1: per-row mean / rstd ----------------
__global__ __launch_bounds__(256) void rowstats_kernel(const float* __restrict__ in1,
                                                       const float* __restrict__ in2,
                                                       float* __restrict__ mu,
                                                       float* __restrict__ rs) {
    __shared__ float s1[4][64], s2[4][64];
    int tt = threadIdx.x & 63, cc = threadIdx.x >> 6;
    int blk = blockIdx.x;            // NB * 64
    int b = blk >> 6;
    int t = ((blk & 63) << 6) + tt;
    float a1 = 0.f, a2 = 0.f;
    for (int i = 0; i < 64; ++i) {
        int c = cc * 64 + i;
        float v = (c < 128) ? in1[(size_t)((b << 7) + c) * LSEQ + t]
                            : in2[(size_t)((b << 7) + (c - 128)) * LSEQ + t];
        a1 += v; a2 += v * v;
    }
    s1[cc][tt] = a1; s2[cc][tt] = a2;
    __syncthreads();
    if (cc == 0) {
        float t1 = s1[0][tt] + s1[1][tt] + s1[2][tt] + s1[3][tt];
        float t2 = s2[0][tt] + s2[1][tt] + s2[2][tt] + s2[3][tt];
        float m = t1 * (1.f / 256.f);
        float var = t2 * (1.f / 256.f) - m * m;
        int r = (b << 12) + t;
        mu[r] = m;
        rs[r] = rsqrtf(var + 1e-5f);
    }
}

// ---------------- Kernel 2: combined weight Wc = Wm(512x256) @ Wo(256x128) ----------------
__global__ __launch_bounds__(256) void wc_kernel(const float* __restrict__ Wm,
                                                 const float* __restrict__ Wo,
                                                 float* __restrict__ Wc) {
    int gid = blockIdx.x * 256 + threadIdx.x;   // 65536
    int row = gid >> 7, col = gid & 127;
    float acc = 0.f;
    for (int k = 0; k < 256; ++k) acc += Wm[row * 256 + k] * Wo[k * 128 + col];
    Wc[gid] = acc;
}

// ---------------- Kernel 3: fused LN + in_proj GEMM ----------------
// xz[r, n] = LN(x[r, :]) @ W[:, n],  M=16384 N=1024 K=256
__global__ __launch_bounds__(256) void gemm1_ln(const float* __restrict__ in1,
                                                const float* __restrict__ in2,
                                                const float* __restrict__ mu,
                                                const float* __restrict__ rs,
                                                const float* __restrict__ g,
                                                const float* __restrict__ beta,
                                                const float* __restrict__ W,
                                                float* __restrict__ xz) {
    __shared__ float As[16][132];
    __shared__ float Bs[16][64];
    __shared__ float smu[128], srs[128], sg[256], sbt[256];
    int tid = threadIdx.x;
    int r0 = blockIdx.x * 128;
    int b  = r0 >> 12;
    int t0 = r0 & 4095;
    int n0 = blockIdx.y * 64;
    int tx = tid & 15, ty = tid >> 4;

    if (tid < 128) { smu[tid] = mu[r0 + tid]; srs[tid] = rs[r0 + tid]; }
    sg[tid] = g[tid & 255]; sbt[tid] = beta[tid & 255];
    __syncthreads();

    float acc[8][4];
    #pragma unroll
    for (int i = 0; i < 8; ++i)
        #pragma unroll
        for (int j = 0; j < 4; ++j) acc[i][j] = 0.f;

    for (int k0 = 0; k0 < 256; k0 += 16) {
        #pragma unroll
        for (int i = 0; i < 8; ++i) {
            int e = tid + i * 256;
            int m = e & 127, kk = e >> 7;
            int c = k0 + kk;
            int t = t0 + m;
            float raw = (c < 128) ? in1[(size_t)((b << 7) + c) * LSEQ + t]
                                  : in2[(size_t)((b << 7) + (c - 128)) * LSEQ + t];
            As[kk][m] = (raw - smu[m]) * srs[m] * sg[c] + sbt[c];
        }
        #pragma unroll
        for (int i = 0; i < 4; ++i) {
            int e = tid + i * 256;
            int n = e & 63, kk = e >> 6;
            Bs[kk][n] = W[(size_t)(k0 + kk) * 1024 + n0 + n];
        }
        __syncthreads();
        #pragma unroll
        for (int kk = 0; kk < 16; ++kk) {
            float4 a0 = *(const float4*)&As[kk][ty * 8];
            float4 a1 = *(const float4*)&As[kk][ty * 8 + 4];
            float4 bv = *(const float4*)&Bs[kk][tx * 4];
            float av[8] = {a0.x, a0.y, a0.z, a0.w, a1.x, a1.y, a1.z, a1.w};
            float bb[4] = {bv.x, bv.y, bv.z, bv.w};
            #pragma unroll
            for (int im = 0; im < 8; ++im)
                #pragma unroll
                for (int jn = 0; jn < 4; ++jn) acc[im][jn] += av[im] * bb[jn];
        }
        __syncthreads();
    }
    #pragma unroll
    for (int im = 0; im < 8; ++im) {
        int r = r0 + ty * 8 + im;
        float4 v = make_float4(acc[im][0], acc[im][1], acc[im][2], acc[im][3]);
        *(float4*)&xz[(size_t)r * 1024 + n0 + tx * 4] = v;
    }
}

// ---------------- Kernel 4: causal depthwise conv(k=4) + SiLU ----------------
__global__ __launch_bounds__(256) void conv_kernel(const float* __restrict__ xz,
                                                   const float* __restrict__ cw,
                                                   const float* __restrict__ cb,
                                                   float* __restrict__ xc) {
    int r = blockIdx.x;
    int b = r >> 12, t = r & 4095;
    #pragma unroll
    for (int i = 0; i < 2; ++i) {
        int d = threadIdx.x + i * 256;
        float acc = cb[d];
        #pragma unroll
        for (int k = 0; k < 4; ++k) {
            int tt = t - 3 + k;
            if (tt >= 0) acc += xz[(size_t)((b << 12) + tt) * 1024 + d] * cw[d * 4 + k];
        }
        xc[(size_t)r * 512 + d] = acc / (1.f + __expf(-acc));   // silu
    }
}

// ---------------- Kernel 5: x_proj GEMM  M=16384 N=48 K=512 ----------------
__global__ __launch_bounds__(256) void xproj_gemm(const float* __restrict__ xc,
                                                  const float* __restrict__ Wxp,
                                                  float* __restrict__ xdbl) {
    __shared__ float Xs[32][65];
    __shared__ float Ws[32][49];
    int tid = threadIdx.x;
    int r0 = blockIdx.x * 64;
    int tx = tid & 15, ty = tid >> 4;
    float acc[4][3];
    #pragma unroll
    for (int i = 0; i < 4; ++i)
        #pragma unroll
        for (int j = 0; j < 3; ++j) acc[i][j] = 0.f;

    for (int k0 = 0; k0 < 512; k0 += 32) {
        #pragma unroll
        for (int i = 0; i < 8; ++i) {
            int e = tid + i * 256;
            int kk = e & 31, m = e >> 5;
            Xs[kk][m] = xc[(size_t)(r0 + m) * 512 + k0 + kk];
        }
        #pragma unroll
        for (int i = 0; i < 6; ++i) {
            int e = tid + i * 256;
            int kk = e / 48, j = e - kk * 48;
            Ws[kk][j] = Wxp[(size_t)(k0 + kk) * 48 + j];
        }
        __syncthreads();
        #pragma unroll
        for (int kk = 0; kk < 32; ++kk) {
            float a[4], w[3];
            #pragma unroll
            for (int i = 0; i < 4; ++i) a[i] = Xs[kk][ty * 4 + i];
            #pragma unroll
            for (int j = 0; j < 3; ++j) w[j] = Ws[kk][tx * 3 + j];
            #pragma unroll
            for (int i = 0; i < 4; ++i)
                #pragma unroll
                for (int j = 0; j < 3; ++j) acc[i][j] += a[i] * w[j];
        }
        __syncthreads();
    }
    #pragma unroll
    for (int i = 0; i < 4; ++i)
        #pragma unroll
        for (int j = 0; j < 3; ++j)
            xdbl[(size_t)(r0 + ty * 4 + i) * 48 + tx * 3 + j] = acc[i][j];
}

// ---------------- Kernel 6: delta = softplus(dt @ Wdt + b) ----------------
__global__ __launch_bounds__(256) void dt_kernel(const float* __restrict__ xdbl,
                                                 const float* __restrict__ Wdt,
                                                 const float* __restrict__ dtb,
                                                 float* __restrict__ delta) {
    __shared__ float sdt[4][16];
    int r0 = blockIdx.x * 4;
    int tid = threadIdx.x;
    if (tid < 64) sdt[tid >> 4][tid & 15] = xdbl[(size_t)(r0 + (tid >> 4)) * 48 + (tid & 15)];
    __syncthreads();
    #pragma unroll
    for (int i = 0; i < 2; ++i) {
        int d = tid + i * 256;
        float bv = dtb[d];
        float a0 = bv, a1 = bv, a2 = bv, a3 = bv;
        #pragma unroll
        for (int q = 0; q < 16; ++q) {
            float w = Wdt[q * 512 + d];
            a0 += sdt[0][q] * w; a1 += sdt[1][q] * w;
            a2 += sdt[2][q] * w; a3 += sdt[3][q] * w;
        }
        delta[(size_t)(r0 + 0) * 512 + d] = softplus_f(a0);
        delta[(size_t)(r0 + 1) * 512 + d] = softplus_f(a1);
        delta[(size_t)(r0 + 2) * 512 + d] = softplus_f(a2);
        delta[(size_t)(r0 + 3) * 512 + d] = softplus_f(a3);
    }
}

// ---------------- Scan pass 1: per-chunk local scan -> (P, h_end) ----------------
// block: 256 threads = 256 channels (half of D_INNER); grid = NB * NCH * 2
// thread owns h[16], P[16] in registers; B[t][n] staged in LDS (broadcast reads).
__global__ __launch_bounds__(256) void scan_pass1(const float* __restrict__ delta,
                                                  const float* __restrict__ xc,
                                                  const float* __restrict__ xdbl,
                                                  const float* __restrict__ A_log,
                                                  float* __restrict__ Parr,
                                                  float* __restrict__ Harr) {
    __shared__ float sB[CHUNK][16];
    int tid = threadIdx.x;
    int chunk = blockIdx.x & (NCH - 1);
    int half  = (blockIdx.x >> 6) & 1;
    int b     = blockIdx.x >> 7;
    int d = half * 256 + tid;
    float Aneg[16];
    #pragma unroll
    for (int n = 0; n < 16; n += 4) {
        float4 v = *(const float4*)&A_log[d * 16 + n];
        Aneg[n] = -__expf(v.x); Aneg[n+1] = -__expf(v.y);
        Aneg[n+2] = -__expf(v.z); Aneg[n+3] = -__expf(v.w);
    }
    int rbase = (b << 12) + chunk * CHUNK;
    #pragma unroll
    for (int i = 0; i < CHUNK * 16 / 256; ++i) {
        int e = tid + i * 256;
        int t = e >> 4, n = e & 15;
        sB[t][n] = xdbl[(size_t)(rbase + t) * 48 + 16 + n];
    }
    __syncthreads();
    float h[16], P[16];
    #pragma unroll
    for (int n = 0; n < 16; ++n) { h[n] = 0.f; P[n] = 1.f; }
    #pragma unroll 4
    for (int t = 0; t < CHUNK; ++t) {
        float dv = delta[(size_t)(rbase + t) * 512 + d];
        float xv = xc[(size_t)(rbase + t) * 512 + d];
        float dx = dv * xv;
        #pragma unroll
        for (int n = 0; n < 16; ++n) {
            float a = __expf(dv * Aneg[n]);
            h[n] = h[n] * a + dx * sB[t][n];
            P[n] *= a;
        }
    }
    size_t gbase = ((size_t)(b * 512 + d)) * 16;
    size_t coff  = (size_t)chunk * 32768;
    #pragma unroll
    for (int n = 0; n < 16; n += 4) {
        *(float4*)&Parr[coff + gbase + n] = make_float4(P[n], P[n+1], P[n+2], P[n+3]);
        *(float4*)&Harr[coff + gbase + n] = make_float4(h[n], h[n+1], h[n+2], h[n+3]);
    }
}

// ---------------- Scan pass 2: sequential carry across chunks ----------------
// thread = (b,d,n); overwrites Harr[c] with the chunk's carry-IN state.
__global__ __launch_bounds__(256) void scan_pass2(const float* __restrict__ Parr,
                                                  float* __restrict__ Harr) {
    int gid = blockIdx.x * 256 + threadIdx.x;   // 32768
    float carry = 0.f;
    for (int c = 0; c < NCH; ++c) {
        size_t off = (size_t)c * 32768 + gid;
        float P = Parr[off], he = Harr[off];
        Harr[off] = carry;
        carry = he + P * carry;
    }
}

// ---------------- Scan pass 3: re-scan with carry-in, fuse D-skip + SiLU gate ----------------
__global__ __launch_bounds__(256) void scan_pass3(const float* __restrict__ delta,
                                                  const float* __restrict__ xc,
                                                  const float* __restrict__ xz,
                                                  const float* __restrict__ xdbl,
                                                  const float* __restrict__ A_log,
                                                  const float* __restrict__ Dp,
                                                  const float* __restrict__ Hin,
                                                  float* __restrict__ yf) {
    __shared__ float sB[CHUNK][16], sC[CHUNK][16];
    int tid = threadIdx.x;
    int chunk = blockIdx.x & (NCH - 1);
    int half  = (blockIdx.x >> 6) & 1;
    int b     = blockIdx.x >> 7;
    int d = half * 256 + tid;
    float Aneg[16];
    #pragma unroll
    for (int n = 0; n < 16; n += 4) {
        float4 v = *(const float4*)&A_log[d * 16 + n];
        Aneg[n] = -__expf(v.x); Aneg[n+1] = -__expf(v.y);
        Aneg[n+2] = -__expf(v.z); Aneg[n+3] = -__expf(v.w);
    }
    float Dv = Dp[d];
    int rbase = (b << 12) + chunk * CHUNK;
    #pragma unroll
    for (int i = 0; i < CHUNK * 16 / 256; ++i) {
        int e = tid + i * 256;
        int t = e >> 4, n = e & 15;
        sB[t][n] = xdbl[(size_t)(rbase + t) * 48 + 16 + n];
        sC[t][n] = xdbl[(size_t)(rbase + t) * 48 + 32 + n];
    }
    __syncthreads();
    size_t gbase = ((size_t)(b * 512 + d)) * 16;
    size_t coff  = (size_t)chunk * 32768;
    float h[16];
    #pragma unroll
    for (int n = 0; n < 16; n += 4) {
        float4 v = *(const float4*)&Hin[coff + gbase + n];
        h[n] = v.x; h[n+1] = v.y; h[n+2] = v.z; h[n+3] = v.w;
    }
    #pragma unroll 4
    for (int t = 0; t < CHUNK; ++t) {
        float dv = delta[(size_t)(rbase + t) * 512 + d];
        float xv = xc[(size_t)(rbase + t) * 512 + d];
        float zv = xz[(size_t)(rbase + t) * 1024 + 512 + d];
        float dx = dv * xv;
        float y = 0.f;
        #pragma unroll
        for (int n = 0; n < 16; ++n) {
            float a = __expf(dv * Aneg[n]);
            h[n] = h[n] * a + dx * sB[t][n];
            y += h[n] * sC[t][n];
        }
        y += xv * Dv;
        y *= zv / (1.f + __expf(-zv));
        yf[(size_t)(rbase + t) * 512 + d] = y;
    }
}

// ---------------- Kernel 8: final GEMM  out = yf @ Wc + bo, transposed store ----------------
__global__ __launch_bounds__(256) void gemm_out(const float* __restrict__ yf,
                                                const float* __restrict__ Wc,
                                                const float* __restrict__ bo,
                                                float* __restrict__ out) {
    __shared__ float As[16][68];
    __shared__ float Bs[16][64];
    int tid = threadIdx.x;
    int r0 = blockIdx.x * 64;
    int c0 = blockIdx.y * 64;
    int b = r0 >> 12, t0 = r0 & 4095;
    int tx = tid & 15, ty = tid >> 4;
    float acc[4][4];
    #pragma unroll
    for (int i = 0; i < 4; ++i)
        #pragma unroll
        for (int j = 0; j < 4; ++j) acc[i][j] = 0.f;

    for (int k0 = 0; k0 < 512; k0 += 16) {
        #pragma unroll
        for (int i = 0; i < 4; ++i) {
            int e = tid + i * 256;
            int kk = e & 15, tl = e >> 4;
            As[kk][tl] = yf[(size_t)(r0 + tl) * 512 + k0 + kk];
        }
        #pragma unroll
        for (int i = 0; i < 4; ++i) {
            int e = tid + i * 256;
            int cc = e & 63, kk = e >> 6;
            Bs[kk][cc] = Wc[(size_t)(k0 + kk) * 128 + c0 + cc];
        }
        __syncthreads();
        #pragma unroll
        for (int kk = 0; kk < 16; ++kk) {
            float4 av = *(const float4*)&As[kk][tx * 4];
            float4 bv = *(const float4*)&Bs[kk][ty * 4];
            float aa[4] = {av.x, av.y, av.z, av.w};
            float bb[4] = {bv.x, bv.y, bv.z, bv.w};
            #pragma unroll
            for (int ci = 0; ci < 4; ++ci)
                #pragma unroll
                for (int tj = 0; tj < 4; ++tj) acc[ci][tj] += bb[ci] * aa[tj];
        }
        __syncthreads();
    }
    #pragma unroll
    for (int ci = 0; ci < 4; ++ci) {
        int c = c0 + ty * 4 + ci;
        float bias = bo[c];
        float4 v = make_float4(acc[ci][0] + bias, acc[ci][1] + bias,
                               acc[ci][2] + bias, acc[ci][3] + bias);
        *(float4*)&out[((size_t)b * 128 + c) * LSEQ + t0 + tx * 4] = v;
    }
}

// ---------------- launch ----------------
extern "C" void kernel_launch(void* const* d_in, const int* in_sizes, int n_in,
                              void* d_out, int out_size, void* d_ws, size_t ws_size,
                              hipStream_t stream) {
    (void)in_sizes; (void)n_in; (void)out_size; (void)ws_size;
    const float* input    = (const float*)d_in[0];
    const float* input2   = (const float*)d_in[1];
    const float* ln_g     = (const float*)d_in[2];
    const float* ln_b     = (const float*)d_in[3];
    const float* outp_w   = (const float*)d_in[4];
    const float* outp_b   = (const float*)d_in[5];
    const float* in_proj  = (const float*)d_in[6];
    const float* conv_w   = (const float*)d_in[7];
    const float* conv_b   = (const float*)d_in[8];
    const float* x_proj   = (const float*)d_in[9];
    const float* dt_w     = (const float*)d_in[10];
    const float* dt_b     = (const float*)d_in[11];
    const float* A_log    = (const float*)d_in[12];
    const float* D_param  = (const float*)d_in[13];
    const float* mout_w   = (const float*)d_in[14];
    float* out = (float*)d_out;

    float* ws = (float*)d_ws;
    float* mu    = ws;                       // 16384
    float* rs    = mu + 16384;               // 16384
    float* xz    = rs + 16384;               // 16384*1024
    float* xc    = xz + (size_t)NR * 1024;   // 16384*512
    float* xdbl  = xc + (size_t)NR * 512;    // 16384*48
    float* delta = xdbl + (size_t)NR * 48;   // 16384*512
    float* yf    = delta + (size_t)NR * 512; // 16384*512
    float* Wc    = yf + (size_t)NR * 512;    // 512*128
    float* Parr  = Wc + 512 * 128;           // NCH*32768
    float* Harr  = Parr + (size_t)NCH * 32768; // NCH*32768

    rowstats_kernel<<<NB * 64, 256, 0, stream>>>(input, input2, mu, rs);
    wc_kernel<<<256, 256, 0, stream>>>(mout_w, outp_w, Wc);
    gemm1_ln<<<dim3(NR / 128, 16), 256, 0, stream>>>(input, input2, mu, rs, ln_g, ln_b,
                                                     in_proj, xz);
    conv_kernel<<<NR, 256, 0, stream>>>(xz, conv_w, conv_b, xc);
    xproj_gemm<<<NR / 64, 256, 0, stream>>>(xc, x_proj, xdbl);
    dt_kernel<<<NR / 4, 256, 0, stream>>>(xdbl, dt_w, dt_b, delta);
    scan_pass1<<<NB * NCH * 2, 256, 0, stream>>>(delta, xc, xdbl, A_log, Parr, Harr);
    scan_pass2<<<128, 256, 0, stream>>>(Parr, Harr);
    scan_pass3<<<NB * NCH * 2, 256, 0, stream>>>(delta, xc, xz, xdbl, A_log, D_param,
                                                 Harr, yf);
    gemm_out<<<dim3(NR / 64, 2), 256, 0, stream>>>(yf, Wc, outp_b, out);
}

// Round 3
// 374.487 us; speedup vs baseline: 2.5256x; 1.2443x over previous
//
#include <hip/hip_runtime.h>
#include <hip/hip_bf16.h>
#include <math.h>

#define LSEQ 4096
#define NR   16384   // B*L
#define NB   4
#define CHUNK 64     // scan chunk length
#define NCH  64      // chunks per sequence (CHUNK*NCH == LSEQ)

typedef short bf16x8 __attribute__((ext_vector_type(8)));
typedef float f32x4  __attribute__((ext_vector_type(4)));

typedef __attribute__((address_space(1))) const void gvoid_t;
typedef __attribute__((address_space(3))) void svoid_t;

__device__ __forceinline__ void gld_lds16(void* lds, const void* g) {
    __builtin_amdgcn_global_load_lds((gvoid_t*)g, (svoid_t*)lds, 16, 0, 0);
}

__device__ __forceinline__ short to_bf16(float f) {
    union { float f; unsigned u; } x; x.f = f;
    unsigned r = (x.u + 0x7fff + ((x.u >> 16) & 1)) >> 16;
    return (short)r;
}

__device__ __forceinline__ float softplus_f(float x) {
    return x > 20.f ? x : log1pf(__expf(x));
}

// ---------------- Kernel 1: per-row mean / rstd ----------------
__global__ __launch_bounds__(256) void rowstats_kernel(const float* __restrict__ in1,
                                                       const float* __restrict__ in2,
                                                       float* __restrict__ mu,
                                                       float* __restrict__ rs) {
    __shared__ float s1[4][64], s2[4][64];
    int tt = threadIdx.x & 63, cc = threadIdx.x >> 6;
    int blk = blockIdx.x;            // NB * 64
    int b = blk >> 6;
    int t = ((blk & 63) << 6) + tt;
    float a1 = 0.f, a2 = 0.f;
    for (int i = 0; i < 64; ++i) {
        int c = cc * 64 + i;
        float v = (c < 128) ? in1[(size_t)((b << 7) + c) * LSEQ + t]
                            : in2[(size_t)((b << 7) + (c - 128)) * LSEQ + t];
        a1 += v; a2 += v * v;
    }
    s1[cc][tt] = a1; s2[cc][tt] = a2;
    __syncthreads();
    if (cc == 0) {
        float t1 = s1[0][tt] + s1[1][tt] + s1[2][tt] + s1[3][tt];
        float t2 = s2[0][tt] + s2[1][tt] + s2[2][tt] + s2[3][tt];
        float m = t1 * (1.f / 256.f);
        float var = t2 * (1.f / 256.f) - m * m;
        int r = (b << 12) + t;
        mu[r] = m;
        rs[r] = rsqrtf(var + 1e-5f);
    }
}

// ---------------- Kernel 1b: LN + transpose + bf16 cast -> Abf[16384][256] ----------------
__global__ __launch_bounds__(256) void ln_bf16_kernel(const float* __restrict__ in1,
                                                      const float* __restrict__ in2,
                                                      const float* __restrict__ mu,
                                                      const float* __restrict__ rs,
                                                      const float* __restrict__ g,
                                                      const float* __restrict__ beta,
                                                      short* __restrict__ Abf) {
    __shared__ float tile[64][65];     // [c][t]
    __shared__ float smu[64], srs[64];
    int b  = blockIdx.z;
    int t0 = blockIdx.x * 64;
    int c0 = blockIdx.y * 64;
    int tid = threadIdx.x;
    int tt = tid & 63, cc = tid >> 6;   // cc 0..3
    if (tid < 64) {
        smu[tid] = mu[(b << 12) + t0 + tid];
        srs[tid] = rs[(b << 12) + t0 + tid];
    }
    #pragma unroll
    for (int i = 0; i < 16; ++i) {
        int c = c0 + cc * 16 + i;
        float raw = (c < 128) ? in1[((size_t)(b * 128 + c)) * LSEQ + t0 + tt]
                              : in2[((size_t)(b * 128 + (c - 128))) * LSEQ + t0 + tt];
        tile[cc * 16 + i][tt] = raw;
    }
    __syncthreads();
    #pragma unroll
    for (int i = 0; i < 16; ++i) {
        int t = cc * 16 + i;
        int c = tt;
        float v = (tile[c][t] - smu[t]) * srs[t] * g[c0 + c] + beta[c0 + c];
        Abf[((size_t)((b << 12) + t0 + t)) * 256 + c0 + c] = to_bf16(v);
    }
}

// ---------------- Kernel 1c: W[256][1024] -> Wt bf16 [1024][256] ----------------
__global__ __launch_bounds__(256) void wt_bf16_kernel(const float* __restrict__ W,
                                                      short* __restrict__ Wt) {
    __shared__ float tile[64][65];     // [k][n]
    int k0 = blockIdx.x * 64;
    int n0 = blockIdx.y * 64;
    int tid = threadIdx.x;
    int a = tid & 63, q = tid >> 6;
    #pragma unroll
    for (int i = 0; i < 16; ++i) {
        int k = q * 16 + i;
        tile[k][a] = W[(size_t)(k0 + k) * 1024 + n0 + a];
    }
    __syncthreads();
    #pragma unroll
    for (int i = 0; i < 16; ++i) {
        int n = q * 16 + i;
        Wt[(size_t)(n0 + n) * 256 + k0 + a] = to_bf16(tile[a][n]);
    }
}

// ---------------- Kernel 2: combined weight Wc = Wm(512x256) @ Wo(256x128) ----------------
__global__ __launch_bounds__(256) void wc_kernel(const float* __restrict__ Wm,
                                                 const float* __restrict__ Wo,
                                                 float* __restrict__ Wc) {
    int gid = blockIdx.x * 256 + threadIdx.x;   // 65536
    int row = gid >> 7, col = gid & 127;
    float acc = 0.f;
    for (int k = 0; k < 256; ++k) acc += Wm[row * 256 + k] * Wo[k * 128 + col];
    Wc[gid] = acc;
}

// ---------------- Kernel 3: MFMA in_proj GEMM  xz = Abf @ Wt^T ----------------
// M=16384 N=1024 K=256; 128x128 tile, 4 waves, 4x4 mfma_f32_16x16x32_bf16, BK=32
__global__ __launch_bounds__(256) void gemm1_mfma(const short* __restrict__ Abf,
                                                  const short* __restrict__ Wt,
                                                  float* __restrict__ xz) {
    __shared__ __align__(16) short Asl[128][32];
    __shared__ __align__(16) short Bsl[128][32];
    int tid = threadIdx.x;
    int wv = tid >> 6, ln = tid & 63;
    int m0 = blockIdx.x * 128;
    int n0 = blockIdx.y * 128;
    int mw = (wv & 1) * 64, nw = (wv >> 1) * 64;

    f32x4 acc[4][4];
    #pragma unroll
    for (int i = 0; i < 4; ++i)
        #pragma unroll
        for (int j = 0; j < 4; ++j) acc[i][j] = (f32x4)(0.f);

    int srow  = ln >> 2;          // 0..15
    int skoff = (ln & 3) * 8;     // 0,8,16,24

    for (int k0 = 0; k0 < 256; k0 += 32) {
        #pragma unroll
        for (int i = 0; i < 2; ++i) {
            int j = wv * 2 + i;   // 0..7 -> 16-row slab
            int row = j * 16 + srow;
            gld_lds16(&Asl[j * 16][0], &Abf[(size_t)(m0 + row) * 256 + k0 + skoff]);
            gld_lds16(&Bsl[j * 16][0], &Wt [(size_t)(n0 + row) * 256 + k0 + skoff]);
        }
        __syncthreads();
        bf16x8 af[4], bff[4];
        int fm = ln & 15, fk = (ln >> 4) * 8;
        #pragma unroll
        for (int i = 0; i < 4; ++i) {
            af[i]  = *(const bf16x8*)&Asl[mw + i * 16 + fm][fk];
            bff[i] = *(const bf16x8*)&Bsl[nw + i * 16 + fm][fk];
        }
        #pragma unroll
        for (int i = 0; i < 4; ++i)
            #pragma unroll
            for (int j = 0; j < 4; ++j)
                acc[i][j] = __builtin_amdgcn_mfma_f32_16x16x32_bf16(af[i], bff[j], acc[i][j], 0, 0, 0);
        __syncthreads();
    }
    int ccol = ln & 15, crow = (ln >> 4) * 4;
    #pragma unroll
    for (int i = 0; i < 4; ++i) {
        #pragma unroll
        for (int j = 0; j < 4; ++j) {
            int n = n0 + nw + j * 16 + ccol;
            #pragma unroll
            for (int r = 0; r < 4; ++r) {
                int m = m0 + mw + i * 16 + crow + r;
                xz[(size_t)m * 1024 + n] = acc[i][j][r];
            }
        }
    }
}

// ---------------- Kernel 4: causal depthwise conv(k=4) + SiLU ----------------
__global__ __launch_bounds__(256) void conv_kernel(const float* __restrict__ xz,
                                                   const float* __restrict__ cw,
                                                   const float* __restrict__ cb,
                                                   float* __restrict__ xc) {
    int r = blockIdx.x;
    int b = r >> 12, t = r & 4095;
    #pragma unroll
    for (int i = 0; i < 2; ++i) {
        int d = threadIdx.x + i * 256;
        float acc = cb[d];
        #pragma unroll
        for (int k = 0; k < 4; ++k) {
            int tt = t - 3 + k;
            if (tt >= 0) acc += xz[(size_t)((b << 12) + tt) * 1024 + d] * cw[d * 4 + k];
        }
        xc[(size_t)r * 512 + d] = acc / (1.f + __expf(-acc));   // silu
    }
}

// ---------------- Kernel 5: x_proj GEMM  M=16384 N=48 K=512 ----------------
__global__ __launch_bounds__(256) void xproj_gemm(const float* __restrict__ xc,
                                                  const float* __restrict__ Wxp,
                                                  float* __restrict__ xdbl) {
    __shared__ float Xs[32][65];
    __shared__ float Ws[32][49];
    int tid = threadIdx.x;
    int r0 = blockIdx.x * 64;
    int tx = tid & 15, ty = tid >> 4;
    float acc[4][3];
    #pragma unroll
    for (int i = 0; i < 4; ++i)
        #pragma unroll
        for (int j = 0; j < 3; ++j) acc[i][j] = 0.f;

    for (int k0 = 0; k0 < 512; k0 += 32) {
        #pragma unroll
        for (int i = 0; i < 8; ++i) {
            int e = tid + i * 256;
            int kk = e & 31, m = e >> 5;
            Xs[kk][m] = xc[(size_t)(r0 + m) * 512 + k0 + kk];
        }
        #pragma unroll
        for (int i = 0; i < 6; ++i) {
            int e = tid + i * 256;
            int kk = e / 48, j = e - kk * 48;
            Ws[kk][j] = Wxp[(size_t)(k0 + kk) * 48 + j];
        }
        __syncthreads();
        #pragma unroll
        for (int kk = 0; kk < 32; ++kk) {
            float a[4], w[3];
            #pragma unroll
            for (int i = 0; i < 4; ++i) a[i] = Xs[kk][ty * 4 + i];
            #pragma unroll
            for (int j = 0; j < 3; ++j) w[j] = Ws[kk][tx * 3 + j];
            #pragma unroll
            for (int i = 0; i < 4; ++i)
                #pragma unroll
                for (int j = 0; j < 3; ++j) acc[i][j] += a[i] * w[j];
        }
        __syncthreads();
    }
    #pragma unroll
    for (int i = 0; i < 4; ++i)
        #pragma unroll
        for (int j = 0; j < 3; ++j)
            xdbl[(size_t)(r0 + ty * 4 + i) * 48 + tx * 3 + j] = acc[i][j];
}

// ---------------- Kernel 6: delta = softplus(dt @ Wdt + b) ----------------
__global__ __launch_bounds__(256) void dt_kernel(const float* __restrict__ xdbl,
                                                 const float* __restrict__ Wdt,
                                                 const float* __restrict__ dtb,
                                                 float* __restrict__ delta) {
    __shared__ float sdt[4][16];
    int r0 = blockIdx.x * 4;
    int tid = threadIdx.x;
    if (tid < 64) sdt[tid >> 4][tid & 15] = xdbl[(size_t)(r0 + (tid >> 4)) * 48 + (tid & 15)];
    __syncthreads();
    #pragma unroll
    for (int i = 0; i < 2; ++i) {
        int d = tid + i * 256;
        float bv = dtb[d];
        float a0 = bv, a1 = bv, a2 = bv, a3 = bv;
        #pragma unroll
        for (int q = 0; q < 16; ++q) {
            float w = Wdt[q * 512 + d];
            a0 += sdt[0][q] * w; a1 += sdt[1][q] * w;
            a2 += sdt[2][q] * w; a3 += sdt[3][q] * w;
        }
        delta[(size_t)(r0 + 0) * 512 + d] = softplus_f(a0);
        delta[(size_t)(r0 + 1) * 512 + d] = softplus_f(a1);
        delta[(size_t)(r0 + 2) * 512 + d] = softplus_f(a2);
        delta[(size_t)(r0 + 3) * 512 + d] = softplus_f(a3);
    }
}

// ---------------- Scan pass 1: per-chunk local scan -> (P, h_end) ----------------
__global__ __launch_bounds__(256) void scan_pass1(const float* __restrict__ delta,
                                                  const float* __restrict__ xc,
                                                  const float* __restrict__ xdbl,
                                                  const float* __restrict__ A_log,
                                                  float* __restrict__ Parr,
                                                  float* __restrict__ Harr) {
    __shared__ float sB[CHUNK][16];
    int tid = threadIdx.x;
    int chunk = blockIdx.x & (NCH - 1);
    int half  = (blockIdx.x >> 6) & 1;
    int b     = blockIdx.x >> 7;
    int d = half * 256 + tid;
    float Aneg[16];
    #pragma unroll
    for (int n = 0; n < 16; n += 4) {
        float4 v = *(const float4*)&A_log[d * 16 + n];
        Aneg[n] = -__expf(v.x); Aneg[n+1] = -__expf(v.y);
        Aneg[n+2] = -__expf(v.z); Aneg[n+3] = -__expf(v.w);
    }
    int rbase = (b << 12) + chunk * CHUNK;
    #pragma unroll
    for (int i = 0; i < CHUNK * 16 / 256; ++i) {
        int e = tid + i * 256;
        int t = e >> 4, n = e & 15;
        sB[t][n] = xdbl[(size_t)(rbase + t) * 48 + 16 + n];
    }
    __syncthreads();
    float h[16], P[16];
    #pragma unroll
    for (int n = 0; n < 16; ++n) { h[n] = 0.f; P[n] = 1.f; }
    #pragma unroll 4
    for (int t = 0; t < CHUNK; ++t) {
        float dv = delta[(size_t)(rbase + t) * 512 + d];
        float xv = xc[(size_t)(rbase + t) * 512 + d];
        float dx = dv * xv;
        #pragma unroll
        for (int n = 0; n < 16; ++n) {
            float a = __expf(dv * Aneg[n]);
            h[n] = h[n] * a + dx * sB[t][n];
            P[n] *= a;
        }
    }
    size_t gbase = ((size_t)(b * 512 + d)) * 16;
    size_t coff  = (size_t)chunk * 32768;
    #pragma unroll
    for (int n = 0; n < 16; n += 4) {
        *(float4*)&Parr[coff + gbase + n] = make_float4(P[n], P[n+1], P[n+2], P[n+3]);
        *(float4*)&Harr[coff + gbase + n] = make_float4(h[n], h[n+1], h[n+2], h[n+3]);
    }
}

// ---------------- Scan pass 2: sequential carry across chunks ----------------
__global__ __launch_bounds__(256) void scan_pass2(const float* __restrict__ Parr,
                                                  float* __restrict__ Harr) {
    int gid = blockIdx.x * 256 + threadIdx.x;   // 32768
    float carry = 0.f;
    for (int c = 0; c < NCH; ++c) {
        size_t off = (size_t)c * 32768 + gid;
        float P = Parr[off], he = Harr[off];
        Harr[off] = carry;
        carry = he + P * carry;
    }
}

// ---------------- Scan pass 3: re-scan with carry-in, fuse D-skip + SiLU gate ----------------
__global__ __launch_bounds__(256) void scan_pass3(const float* __restrict__ delta,
                                                  const float* __restrict__ xc,
                                                  const float* __restrict__ xz,
                                                  const float* __restrict__ xdbl,
                                                  const float* __restrict__ A_log,
                                                  const float* __restrict__ Dp,
                                                  const float* __restrict__ Hin,
                                                  float* __restrict__ yf) {
    __shared__ float sB[CHUNK][16], sC[CHUNK][16];
    int tid = threadIdx.x;
    int chunk = blockIdx.x & (NCH - 1);
    int half  = (blockIdx.x >> 6) & 1;
    int b     = blockIdx.x >> 7;
    int d = half * 256 + tid;
    float Aneg[16];
    #pragma unroll
    for (int n = 0; n < 16; n += 4) {
        float4 v = *(const float4*)&A_log[d * 16 + n];
        Aneg[n] = -__expf(v.x); Aneg[n+1] = -__expf(v.y);
        Aneg[n+2] = -__expf(v.z); Aneg[n+3] = -__expf(v.w);
    }
    float Dv = Dp[d];
    int rbase = (b << 12) + chunk * CHUNK;
    #pragma unroll
    for (int i = 0; i < CHUNK * 16 / 256; ++i) {
        int e = tid + i * 256;
        int t = e >> 4, n = e & 15;
        sB[t][n] = xdbl[(size_t)(rbase + t) * 48 + 16 + n];
        sC[t][n] = xdbl[(size_t)(rbase + t) * 48 + 32 + n];
    }
    __syncthreads();
    size_t gbase = ((size_t)(b * 512 + d)) * 16;
    size_t coff  = (size_t)chunk * 32768;
    float h[16];
    #pragma unroll
    for (int n = 0; n < 16; n += 4) {
        float4 v = *(const float4*)&Hin[coff + gbase + n];
        h[n] = v.x; h[n+1] = v.y; h[n+2] = v.z; h[n+3] = v.w;
    }
    #pragma unroll 4
    for (int t = 0; t < CHUNK; ++t) {
        float dv = delta[(size_t)(rbase + t) * 512 + d];
        float xv = xc[(size_t)(rbase + t) * 512 + d];
        float zv = xz[(size_t)(rbase + t) * 1024 + 512 + d];
        float dx = dv * xv;
        float y = 0.f;
        #pragma unroll
        for (int n = 0; n < 16; ++n) {
            float a = __expf(dv * Aneg[n]);
            h[n] = h[n] * a + dx * sB[t][n];
            y += h[n] * sC[t][n];
        }
        y += xv * Dv;
        y *= zv / (1.f + __expf(-zv));
        yf[(size_t)(rbase + t) * 512 + d] = y;
    }
}

// ---------------- Kernel 8: final GEMM  out = yf @ Wc + bo, transposed store ----------------
__global__ __launch_bounds__(256) void gemm_out(const float* __restrict__ yf,
                                                const float* __restrict__ Wc,
                                                const float* __restrict__ bo,
                                                float* __restrict__ out) {
    __shared__ float As[16][68];
    __shared__ float Bs[16][64];
    int tid = threadIdx.x;
    int r0 = blockIdx.x * 64;
    int c0 = blockIdx.y * 64;
    int b = r0 >> 12, t0 = r0 & 4095;
    int tx = tid & 15, ty = tid >> 4;
    float acc[4][4];
    #pragma unroll
    for (int i = 0; i < 4; ++i)
        #pragma unroll
        for (int j = 0; j < 4; ++j) acc[i][j] = 0.f;

    for (int k0 = 0; k0 < 512; k0 += 16) {
        #pragma unroll
        for (int i = 0; i < 4; ++i) {
            int e = tid + i * 256;
            int kk = e & 15, tl = e >> 4;
            As[kk][tl] = yf[(size_t)(r0 + tl) * 512 + k0 + kk];
        }
        #pragma unroll
        for (int i = 0; i < 4; ++i) {
            int e = tid + i * 256;
            int cc = e & 63, kk = e >> 6;
            Bs[kk][cc] = Wc[(size_t)(k0 + kk) * 128 + c0 + cc];
        }
        __syncthreads();
        #pragma unroll
        for (int kk = 0; kk < 16; ++kk) {
            float4 av = *(const float4*)&As[kk][tx * 4];
            float4 bv = *(const float4*)&Bs[kk][ty * 4];
            float aa[4] = {av.x, av.y, av.z, av.w};
            float bb[4] = {bv.x, bv.y, bv.z, bv.w};
            #pragma unroll
            for (int ci = 0; ci < 4; ++ci)
                #pragma unroll
                for (int tj = 0; tj < 4; ++tj) acc[ci][tj] += bb[ci] * aa[tj];
        }
        __syncthreads();
    }
    #pragma unroll
    for (int ci = 0; ci < 4; ++ci) {
        int c = c0 + ty * 4 + ci;
        float bias = bo[c];
        float4 v = make_float4(acc[ci][0] + bias, acc[ci][1] + bias,
                               acc[ci][2] + bias, acc[ci][3] + bias);
        *(float4*)&out[((size_t)b * 128 + c) * LSEQ + t0 + tx * 4] = v;
    }
}

// ---------------- launch ----------------
extern "C" void kernel_launch(void* const* d_in, const int* in_sizes, int n_in,
                              void* d_out, int out_size, void* d_ws, size_t ws_size,
                              hipStream_t stream) {
    (void)in_sizes; (void)n_in; (void)out_size; (void)ws_size;
    const float* input    = (const float*)d_in[0];
    const float* input2   = (const float*)d_in[1];
    const float* ln_g     = (const float*)d_in[2];
    const float* ln_b     = (const float*)d_in[3];
    const float* outp_w   = (const float*)d_in[4];
    const float* outp_b   = (const float*)d_in[5];
    const float* in_proj  = (const float*)d_in[6];
    const float* conv_w   = (const float*)d_in[7];
    const float* conv_b   = (const float*)d_in[8];
    const float* x_proj   = (const float*)d_in[9];
    const float* dt_w     = (const float*)d_in[10];
    const float* dt_b     = (const float*)d_in[11];
    const float* A_log    = (const float*)d_in[12];
    const float* D_param  = (const float*)d_in[13];
    const float* mout_w   = (const float*)d_in[14];
    float* out = (float*)d_out;

    float* ws = (float*)d_ws;
    float* mu    = ws;                       // 16384
    float* rs    = mu + 16384;               // 16384
    float* xz    = rs + 16384;               // 16384*1024
    float* xc    = xz + (size_t)NR * 1024;   // 16384*512
    float* xdbl  = xc + (size_t)NR * 512;    // 16384*48
    float* delta = xdbl + (size_t)NR * 48;   // 16384*512
    float* yf    = delta + (size_t)NR * 512; // 16384*512
    float* Wc    = yf + (size_t)NR * 512;    // 512*128
    float* Parr  = Wc + 512 * 128;           // NCH*32768
    float* Harr  = Parr + (size_t)NCH * 32768; // NCH*32768
    short* Abf   = (short*)(Harr + (size_t)NCH * 32768);  // 16384*256 bf16
    short* Wt    = Abf + (size_t)NR * 256;                // 1024*256 bf16

    rowstats_kernel<<<NB * 64, 256, 0, stream>>>(input, input2, mu, rs);
    ln_bf16_kernel<<<dim3(64, 4, NB), 256, 0, stream>>>(input, input2, mu, rs,
                                                        ln_g, ln_b, Abf);
    wt_bf16_kernel<<<dim3(4, 16), 256, 0, stream>>>(in_proj, Wt);
    wc_kernel<<<256, 256, 0, stream>>>(mout_w, outp_w, Wc);
    gemm1_mfma<<<dim3(128, 8), 256, 0, stream>>>(Abf, Wt, xz);
    conv_kernel<<<NR, 256, 0, stream>>>(xz, conv_w, conv_b, xc);
    xproj_gemm<<<NR / 64, 256, 0, stream>>>(xc, x_proj, xdbl);
    dt_kernel<<<NR / 4, 256, 0, stream>>>(xdbl, dt_w, dt_b, delta);
    scan_pass1<<<NB * NCH * 2, 256, 0, stream>>>(delta, xc, xdbl, A_log, Parr, Harr);
    scan_pass2<<<128, 256, 0, stream>>>(Parr, Harr);
    scan_pass3<<<NB * NCH * 2, 256, 0, stream>>>(delta, xc, xz, xdbl, A_log, D_param,
                                                 Harr, yf);
    gemm_out<<<dim3(NR / 64, 2), 256, 0, stream>>>(yf, Wc, outp_b, out);
}

// Round 4
// 311.865 us; speedup vs baseline: 3.0328x; 1.2008x over previous
//
#include <hip/hip_runtime.h>
#include <hip/hip_bf16.h>
#include <math.h>

#define LSEQ 4096
#define NR   16384   // B*L
#define NB   4
#define CHUNK 64
#define NCH  64

typedef short bf16x8 __attribute__((ext_vector_type(8)));
typedef float f32x4  __attribute__((ext_vector_type(4)));

typedef __attribute__((address_space(1))) const void gvoid_t;
typedef __attribute__((address_space(3))) void svoid_t;

__device__ __forceinline__ void gld_lds16(void* lds, const void* g) {
    __builtin_amdgcn_global_load_lds((gvoid_t*)g, (svoid_t*)lds, 16, 0, 0);
}

__device__ __forceinline__ unsigned short to_bf16(float f) {
    union { float f; unsigned u; } x; x.f = f;
    unsigned r = (x.u + 0x7fff + ((x.u >> 16) & 1)) >> 16;
    return (unsigned short)r;
}
__device__ __forceinline__ float bf2f(unsigned short u) {
    union { unsigned u; float f; } x; x.u = ((unsigned)u) << 16;
    return x.f;
}
__device__ __forceinline__ float softplus_f(float x) {
    return x > 20.f ? x : log1pf(__expf(x));
}
__device__ __forceinline__ float silu_f(float x) {
    return x / (1.f + __expf(-x));
}

// ---------------- K1: fused rowstats + LN + transpose + bf16 cast ----------------
// grid (128 t-tiles, NB); 32 t-rows per block
__global__ __launch_bounds__(256) void ln_fused(const float* __restrict__ in1,
                                                const float* __restrict__ in2,
                                                const float* __restrict__ g,
                                                const float* __restrict__ beta,
                                                unsigned short* __restrict__ Abf) {
    __shared__ float tile[256][33];
    __shared__ float s1[8][32], s2[8][32];
    __shared__ float smu[32], srs[32];
    int tid = threadIdx.x;
    int t0 = blockIdx.x * 32;
    int b  = blockIdx.y;
    // load 256c x 32t
    #pragma unroll
    for (int p = 0; p < 8; ++p) {
        int c = p * 32 + (tid >> 3);
        int toff = (tid & 7) * 4;
        const float* src = (c < 128) ? &in1[((size_t)(b * 128 + c)) * LSEQ + t0 + toff]
                                     : &in2[((size_t)(b * 128 + (c - 128))) * LSEQ + t0 + toff];
        float4 v = *(const float4*)src;
        tile[c][toff] = v.x; tile[c][toff+1] = v.y;
        tile[c][toff+2] = v.z; tile[c][toff+3] = v.w;
    }
    __syncthreads();
    {
        int t = tid & 31, gg = tid >> 5;
        float a1 = 0.f, a2 = 0.f;
        #pragma unroll
        for (int i = 0; i < 32; ++i) {
            float v = tile[gg * 32 + i][t];
            a1 += v; a2 += v * v;
        }
        s1[gg][t] = a1; s2[gg][t] = a2;
    }
    __syncthreads();
    if (tid < 32) {
        float a1 = 0.f, a2 = 0.f;
        #pragma unroll
        for (int gg = 0; gg < 8; ++gg) { a1 += s1[gg][tid]; a2 += s2[gg][tid]; }
        float m = a1 * (1.f / 256.f);
        float var = a2 * (1.f / 256.f) - m * m;
        smu[tid] = m;
        srs[tid] = rsqrtf(var + 1e-5f);
    }
    __syncthreads();
    int c = tid;
    float gc = g[c], bc = beta[c];
    #pragma unroll 4
    for (int t = 0; t < 32; ++t) {
        float v = (tile[c][t] - smu[t]) * srs[t] * gc + bc;
        Abf[((size_t)((b << 12) + t0 + t)) * 256 + c] = to_bf16(v);
    }
}

// ---------------- K2: W[256][1024] -> Wt bf16 [1024][256] ----------------
__global__ __launch_bounds__(256) void wt_bf16_kernel(const float* __restrict__ W,
                                                      unsigned short* __restrict__ Wt) {
    __shared__ float tile[64][65];
    int k0 = blockIdx.x * 64;
    int n0 = blockIdx.y * 64;
    int tid = threadIdx.x;
    int a = tid & 63, q = tid >> 6;
    #pragma unroll
    for (int i = 0; i < 16; ++i) {
        int k = q * 16 + i;
        tile[k][a] = W[(size_t)(k0 + k) * 1024 + n0 + a];
    }
    __syncthreads();
    #pragma unroll
    for (int i = 0; i < 16; ++i) {
        int n = q * 16 + i;
        Wt[(size_t)(n0 + n) * 256 + k0 + a] = to_bf16(tile[a][n]);
    }
}

// ---------------- K3: WcT bf16 [128 c][512 k] = (Wm @ Wo)^T ----------------
__global__ __launch_bounds__(256) void wct_kernel(const float* __restrict__ Wm,
                                                  const float* __restrict__ Wo,
                                                  unsigned short* __restrict__ WcT) {
    int gid = blockIdx.x * 256 + threadIdx.x;   // 65536
    int row = gid >> 7, col = gid & 127;        // row: d_inner, col: c
    float acc = 0.f;
    for (int k = 0; k < 256; ++k) acc += Wm[row * 256 + k] * Wo[k * 128 + col];
    WcT[(size_t)col * 512 + row] = to_bf16(acc);
}

// ---------------- K4: MFMA in_proj GEMM, silu on z half, bf16 out ----------------
// M=16384 N=1024 K=256; 128x128 tile
__global__ __launch_bounds__(256) void gemm1_mfma(const unsigned short* __restrict__ Abf,
                                                  const unsigned short* __restrict__ Wt,
                                                  unsigned short* __restrict__ xh,
                                                  unsigned short* __restrict__ zs) {
    __shared__ __align__(16) short Asl[128][32];
    __shared__ __align__(16) short Bsl[128][32];
    int tid = threadIdx.x;
    int wv = tid >> 6, ln = tid & 63;
    int m0 = blockIdx.x * 128;
    int n0 = blockIdx.y * 128;
    int mw = (wv & 1) * 64, nw = (wv >> 1) * 64;

    f32x4 acc[4][4];
    #pragma unroll
    for (int i = 0; i < 4; ++i)
        #pragma unroll
        for (int j = 0; j < 4; ++j) acc[i][j] = (f32x4)(0.f);

    int srow  = ln >> 2;
    int skoff = (ln & 3) * 8;

    for (int k0 = 0; k0 < 256; k0 += 32) {
        #pragma unroll
        for (int i = 0; i < 2; ++i) {
            int j = wv * 2 + i;
            int row = j * 16 + srow;
            gld_lds16(&Asl[j * 16][0], &Abf[(size_t)(m0 + row) * 256 + k0 + skoff]);
            gld_lds16(&Bsl[j * 16][0], &Wt [(size_t)(n0 + row) * 256 + k0 + skoff]);
        }
        __syncthreads();
        bf16x8 af[4], bff[4];
        int fm = ln & 15, fk = (ln >> 4) * 8;
        #pragma unroll
        for (int i = 0; i < 4; ++i) {
            af[i]  = *(const bf16x8*)&Asl[mw + i * 16 + fm][fk];
            bff[i] = *(const bf16x8*)&Bsl[nw + i * 16 + fm][fk];
        }
        #pragma unroll
        for (int i = 0; i < 4; ++i)
            #pragma unroll
            for (int j = 0; j < 4; ++j)
                acc[i][j] = __builtin_amdgcn_mfma_f32_16x16x32_bf16(af[i], bff[j], acc[i][j], 0, 0, 0);
        __syncthreads();
    }
    int ccol = ln & 15, crow = (ln >> 4) * 4;
    bool zhalf = (n0 >= 512);
    #pragma unroll
    for (int i = 0; i < 4; ++i) {
        #pragma unroll
        for (int j = 0; j < 4; ++j) {
            int n = n0 + nw + j * 16 + ccol;
            #pragma unroll
            for (int r = 0; r < 4; ++r) {
                int m = m0 + mw + i * 16 + crow + r;
                float v = acc[i][j][r];
                if (zhalf) zs[(size_t)m * 512 + (n - 512)] = to_bf16(silu_f(v));
                else       xh[(size_t)m * 512 + n]         = to_bf16(v);
            }
        }
    }
}

// ---------------- K5: fused conv + SiLU + xproj + dt ----------------
// 32 rows per block; grid NR/32 = 512
#define XSTR 516   // bf16 elems per LDS row (bank-conflict-free for xproj)
__global__ __launch_bounds__(256) void fused_cxd(const unsigned short* __restrict__ xh,
                                                 const float* __restrict__ cw,
                                                 const float* __restrict__ cb,
                                                 const float* __restrict__ Wxp,
                                                 const float* __restrict__ Wdt,
                                                 const float* __restrict__ dtb,
                                                 unsigned short* __restrict__ xcg,
                                                 unsigned short* __restrict__ deltag,
                                                 float* __restrict__ Bc,
                                                 float* __restrict__ Cc) {
    __shared__ unsigned short sxh[35 * XSTR];   // 35 rows (t0-3..t0+31), conv out reuses slots
    __shared__ float sW[64][48];
    __shared__ float sdbl[32][49];
    int tid = threadIdx.x;
    int r0 = blockIdx.x * 32;
    int b  = r0 >> 12;
    int t0 = r0 & 4095;

    // ---- load x rows t0-3 .. t0+31 (uint = 2 bf16) ----
    {
        const unsigned* xh32 = (const unsigned*)xh;
        #pragma unroll
        for (int it = 0; it < 35; ++it) {
            int idx = tid + it * 256;
            int slot = idx >> 8, u = idx & 255;
            int tglob = t0 - 3 + slot;
            unsigned v = 0;
            if (tglob >= 0) v = xh32[((size_t)((b << 12) + tglob) * 512 + u * 2) >> 1];
            *(unsigned*)&sxh[slot * XSTR + u * 2] = v;
        }
    }
    __syncthreads();

    // ---- conv + silu (per-column private, in-place slot reuse) ----
    {
        #pragma unroll
        for (int half = 0; half < 2; ++half) {
            int d = tid + half * 256;
            float4 w4 = *(const float4*)&cw[d * 4];
            float bv = cb[d];
            #pragma unroll 4
            for (int r = 0; r < 32; ++r) {
                float a = bv;
                a += bf2f(sxh[(r + 0) * XSTR + d]) * w4.x;
                a += bf2f(sxh[(r + 1) * XSTR + d]) * w4.y;
                a += bf2f(sxh[(r + 2) * XSTR + d]) * w4.z;
                a += bf2f(sxh[(r + 3) * XSTR + d]) * w4.w;
                float v = silu_f(a);
                unsigned short bv16 = to_bf16(v);
                sxh[r * XSTR + d] = bv16;             // slot r now holds xc row r
                xcg[(size_t)(r0 + r) * 512 + d] = bv16;
            }
        }
    }
    __syncthreads();

    // ---- xproj: xdbl[32][48] = xc @ Wxp, K=512 ----
    {
        int rg = tid >> 4;          // 16 groups x 2 rows
        int cg = tid & 15;          // 16 groups x 3 cols
        float acc[2][3] = {{0.f,0.f,0.f},{0.f,0.f,0.f}};
        for (int k0 = 0; k0 < 512; k0 += 64) {
            __syncthreads();
            #pragma unroll
            for (int i = 0; i < 12; ++i) {
                int idx = tid + i * 256;
                ((float*)sW)[idx] = Wxp[(size_t)k0 * 48 + idx];
            }
            __syncthreads();
            #pragma unroll 8
            for (int k = 0; k < 64; ++k) {
                float x0 = bf2f(sxh[(rg * 2 + 0) * XSTR + k0 + k]);
                float x1 = bf2f(sxh[(rg * 2 + 1) * XSTR + k0 + k]);
                float w0 = sW[k][cg * 3 + 0];
                float w1 = sW[k][cg * 3 + 1];
                float w2 = sW[k][cg * 3 + 2];
                acc[0][0] += x0 * w0; acc[0][1] += x0 * w1; acc[0][2] += x0 * w2;
                acc[1][0] += x1 * w0; acc[1][1] += x1 * w1; acc[1][2] += x1 * w2;
            }
        }
        #pragma unroll
        for (int ri = 0; ri < 2; ++ri)
            #pragma unroll
            for (int j = 0; j < 3; ++j)
                sdbl[rg * 2 + ri][cg * 3 + j] = acc[ri][j];
    }
    __syncthreads();

    // ---- write B, C ----
    #pragma unroll
    for (int i = 0; i < 4; ++i) {
        int e = tid + i * 256;
        int r = e >> 5, q = e & 31;
        float v = sdbl[r][16 + q];
        if (q < 16) Bc[(size_t)(r0 + r) * 16 + q] = v;
        else        Cc[(size_t)(r0 + r) * 16 + (q - 16)] = v;
    }

    // ---- dt: delta[32][512] = softplus(dt @ Wdt + b) ----
    {
        int d0 = tid, d1 = tid + 256;
        float w0[16], w1[16];
        #pragma unroll
        for (int q = 0; q < 16; ++q) {
            w0[q] = Wdt[q * 512 + d0];
            w1[q] = Wdt[q * 512 + d1];
        }
        float b0 = dtb[d0], b1 = dtb[d1];
        #pragma unroll 2
        for (int r = 0; r < 32; ++r) {
            float a0 = b0, a1 = b1;
            #pragma unroll
            for (int q = 0; q < 16; ++q) {
                float s = sdbl[r][q];
                a0 += s * w0[q]; a1 += s * w1[q];
            }
            deltag[(size_t)(r0 + r) * 512 + d0] = to_bf16(softplus_f(a0));
            deltag[(size_t)(r0 + r) * 512 + d1] = to_bf16(softplus_f(a1));
        }
    }
}

// ---------------- K6: scan pass 1 ----------------
__global__ __launch_bounds__(256) void scan_pass1(const unsigned short* __restrict__ deltag,
                                                  const unsigned short* __restrict__ xcg,
                                                  const float* __restrict__ Bc,
                                                  const float* __restrict__ A_log,
                                                  float* __restrict__ Parr,
                                                  float* __restrict__ Harr) {
    __shared__ float sB[CHUNK][16];
    int tid = threadIdx.x;
    int chunk = blockIdx.x & (NCH - 1);
    int half  = (blockIdx.x >> 6) & 1;
    int b     = blockIdx.x >> 7;
    int d = half * 256 + tid;
    float Aneg[16];
    #pragma unroll
    for (int n = 0; n < 16; n += 4) {
        float4 v = *(const float4*)&A_log[d * 16 + n];
        Aneg[n] = -__expf(v.x); Aneg[n+1] = -__expf(v.y);
        Aneg[n+2] = -__expf(v.z); Aneg[n+3] = -__expf(v.w);
    }
    int rbase = (b << 12) + chunk * CHUNK;
    #pragma unroll
    for (int i = 0; i < 4; ++i) {
        int e = tid + i * 256;
        int t = e >> 4, n = e & 15;
        sB[t][n] = Bc[(size_t)(rbase + t) * 16 + n];
    }
    __syncthreads();
    float h[16];
    float S = 0.f;
    #pragma unroll
    for (int n = 0; n < 16; ++n) h[n] = 0.f;
    #pragma unroll 4
    for (int t = 0; t < CHUNK; ++t) {
        float dv = bf2f(deltag[(size_t)(rbase + t) * 512 + d]);
        float xv = bf2f(xcg[(size_t)(rbase + t) * 512 + d]);
        float dx = dv * xv;
        S += dv;
        #pragma unroll
        for (int n = 0; n < 16; ++n) {
            float a = __expf(dv * Aneg[n]);
            h[n] = h[n] * a + dx * sB[t][n];
        }
    }
    size_t gbase = ((size_t)(b * 512 + d)) * 16;
    size_t coff  = (size_t)chunk * 32768;
    #pragma unroll
    for (int n = 0; n < 16; n += 4) {
        *(float4*)&Parr[coff + gbase + n] = make_float4(__expf(S * Aneg[n]), __expf(S * Aneg[n+1]),
                                                        __expf(S * Aneg[n+2]), __expf(S * Aneg[n+3]));
        *(float4*)&Harr[coff + gbase + n] = make_float4(h[n], h[n+1], h[n+2], h[n+3]);
    }
}

// ---------------- K7: scan pass 2 (carry across chunks) ----------------
__global__ __launch_bounds__(256) void scan_pass2(const float* __restrict__ Parr,
                                                  float* __restrict__ Harr) {
    int gid = blockIdx.x * 256 + threadIdx.x;   // 32768
    float carry = 0.f;
    #pragma unroll 8
    for (int c = 0; c < NCH; ++c) {
        size_t off = (size_t)c * 32768 + gid;
        float P = Parr[off], he = Harr[off];
        Harr[off] = carry;
        carry = he + P * carry;
    }
}

// ---------------- K8: scan pass 3 + D-skip + gating ----------------
__global__ __launch_bounds__(256) void scan_pass3(const unsigned short* __restrict__ deltag,
                                                  const unsigned short* __restrict__ xcg,
                                                  const unsigned short* __restrict__ zs,
                                                  const float* __restrict__ Bc,
                                                  const float* __restrict__ Cc,
                                                  const float* __restrict__ A_log,
                                                  const float* __restrict__ Dp,
                                                  const float* __restrict__ Hin,
                                                  unsigned short* __restrict__ yf16) {
    __shared__ float2 sBC[CHUNK][16];
    int tid = threadIdx.x;
    int chunk = blockIdx.x & (NCH - 1);
    int half  = (blockIdx.x >> 6) & 1;
    int b     = blockIdx.x >> 7;
    int d = half * 256 + tid;
    float Aneg[16];
    #pragma unroll
    for (int n = 0; n < 16; n += 4) {
        float4 v = *(const float4*)&A_log[d * 16 + n];
        Aneg[n] = -__expf(v.x); Aneg[n+1] = -__expf(v.y);
        Aneg[n+2] = -__expf(v.z); Aneg[n+3] = -__expf(v.w);
    }
    float Dv = Dp[d];
    int rbase = (b << 12) + chunk * CHUNK;
    #pragma unroll
    for (int i = 0; i < 4; ++i) {
        int e = tid + i * 256;
        int t = e >> 4, n = e & 15;
        sBC[t][n] = make_float2(Bc[(size_t)(rbase + t) * 16 + n],
                                Cc[(size_t)(rbase + t) * 16 + n]);
    }
    __syncthreads();
    size_t gbase = ((size_t)(b * 512 + d)) * 16;
    size_t coff  = (size_t)chunk * 32768;
    float h[16];
    #pragma unroll
    for (int n = 0; n < 16; n += 4) {
        float4 v = *(const float4*)&Hin[coff + gbase + n];
        h[n] = v.x; h[n+1] = v.y; h[n+2] = v.z; h[n+3] = v.w;
    }
    #pragma unroll 4
    for (int t = 0; t < CHUNK; ++t) {
        float dv = bf2f(deltag[(size_t)(rbase + t) * 512 + d]);
        float xv = bf2f(xcg[(size_t)(rbase + t) * 512 + d]);
        float zv = bf2f(zs[(size_t)(rbase + t) * 512 + d]);   // silu pre-applied
        float dx = dv * xv;
        float y = 0.f;
        #pragma unroll
        for (int n = 0; n < 16; ++n) {
            float2 bc = sBC[t][n];
            float a = __expf(dv * Aneg[n]);
            h[n] = h[n] * a + dx * bc.x;
            y += h[n] * bc.y;
        }
        y += xv * Dv;
        y *= zv;
        yf16[(size_t)(rbase + t) * 512 + d] = to_bf16(y);
    }
}

// ---------------- K9: MFMA out GEMM  out[c][t] = WcT @ yf^T + bias ----------------
// A = WcT[128][512], B = yf[16384][512]; tile 128(c) x 64(t); 256 blocks
__global__ __launch_bounds__(256) void gemm_out_mfma(const unsigned short* __restrict__ WcT,
                                                     const unsigned short* __restrict__ yf16,
                                                     const float* __restrict__ bo,
                                                     float* __restrict__ out) {
    __shared__ __align__(16) short Asl[128][32];
    __shared__ __align__(16) short Bsl[64][32];
    int tid = threadIdx.x;
    int wv = tid >> 6, ln = tid & 63;
    int n0 = blockIdx.x * 64;         // global row (t) base
    int mw = (wv & 1) * 64, nw = (wv >> 1) * 32;

    f32x4 acc[4][2];
    #pragma unroll
    for (int i = 0; i < 4; ++i)
        #pragma unroll
        for (int j = 0; j < 2; ++j) acc[i][j] = (f32x4)(0.f);

    int srow  = ln >> 2;
    int skoff = (ln & 3) * 8;

    for (int k0 = 0; k0 < 512; k0 += 32) {
        #pragma unroll
        for (int i = 0; i < 2; ++i) {
            int j = wv * 2 + i;
            int row = j * 16 + srow;
            gld_lds16(&Asl[j * 16][0], &WcT[(size_t)row * 512 + k0 + skoff]);
        }
        {
            int row = wv * 16 + srow;
            gld_lds16(&Bsl[wv * 16][0], &yf16[(size_t)(n0 + row) * 512 + k0 + skoff]);
        }
        __syncthreads();
        bf16x8 af[4], bff[2];
        int fm = ln & 15, fk = (ln >> 4) * 8;
        #pragma unroll
        for (int i = 0; i < 4; ++i) af[i]  = *(const bf16x8*)&Asl[mw + i * 16 + fm][fk];
        #pragma unroll
        for (int j = 0; j < 2; ++j) bff[j] = *(const bf16x8*)&Bsl[nw + j * 16 + fm][fk];
        #pragma unroll
        for (int i = 0; i < 4; ++i)
            #pragma unroll
            for (int j = 0; j < 2; ++j)
                acc[i][j] = __builtin_amdgcn_mfma_f32_16x16x32_bf16(af[i], bff[j], acc[i][j], 0, 0, 0);
        __syncthreads();
    }
    int ccol = ln & 15, crow = (ln >> 4) * 4;
    int b = n0 >> 12, tb = n0 & 4095;
    #pragma unroll
    for (int i = 0; i < 4; ++i) {
        #pragma unroll
        for (int r = 0; r < 4; ++r) {
            int c = mw + i * 16 + crow + r;
            float bias = bo[c];
            #pragma unroll
            for (int j = 0; j < 2; ++j) {
                int t = tb + nw + j * 16 + ccol;
                out[((size_t)(b * 128 + c)) * LSEQ + t] = acc[i][j][r] + bias;
            }
        }
    }
}

// ---------------- launch ----------------
extern "C" void kernel_launch(void* const* d_in, const int* in_sizes, int n_in,
                              void* d_out, int out_size, void* d_ws, size_t ws_size,
                              hipStream_t stream) {
    (void)in_sizes; (void)n_in; (void)out_size; (void)ws_size;
    const float* input    = (const float*)d_in[0];
    const float* input2   = (const float*)d_in[1];
    const float* ln_g     = (const float*)d_in[2];
    const float* ln_b     = (const float*)d_in[3];
    const float* outp_w   = (const float*)d_in[4];
    const float* outp_b   = (const float*)d_in[5];
    const float* in_proj  = (const float*)d_in[6];
    const float* conv_w   = (const float*)d_in[7];
    const float* conv_b   = (const float*)d_in[8];
    const float* x_proj   = (const float*)d_in[9];
    const float* dt_w     = (const float*)d_in[10];
    const float* dt_b     = (const float*)d_in[11];
    const float* A_log    = (const float*)d_in[12];
    const float* D_param  = (const float*)d_in[13];
    const float* mout_w   = (const float*)d_in[14];
    float* out = (float*)d_out;

    char* ws = (char*)d_ws;
    unsigned short* xh    = (unsigned short*)ws;                    ws += (size_t)NR * 512 * 2;
    unsigned short* zsbuf = (unsigned short*)ws;                    ws += (size_t)NR * 512 * 2;
    unsigned short* xcg   = (unsigned short*)ws;                    ws += (size_t)NR * 512 * 2;
    unsigned short* dlt   = (unsigned short*)ws;                    ws += (size_t)NR * 512 * 2;
    unsigned short* yf16  = (unsigned short*)ws;                    ws += (size_t)NR * 512 * 2;
    unsigned short* Abf   = (unsigned short*)ws;                    ws += (size_t)NR * 256 * 2;
    unsigned short* Wt    = (unsigned short*)ws;                    ws += (size_t)1024 * 256 * 2;
    unsigned short* WcT   = (unsigned short*)ws;                    ws += (size_t)128 * 512 * 2;
    float* Bc   = (float*)ws;                                       ws += (size_t)NR * 16 * 4;
    float* Cc   = (float*)ws;                                       ws += (size_t)NR * 16 * 4;
    float* Parr = (float*)ws;                                       ws += (size_t)NCH * 32768 * 4;
    float* Harr = (float*)ws;                                       ws += (size_t)NCH * 32768 * 4;

    ln_fused<<<dim3(128, NB), 256, 0, stream>>>(input, input2, ln_g, ln_b, Abf);
    wt_bf16_kernel<<<dim3(4, 16), 256, 0, stream>>>(in_proj, Wt);
    wct_kernel<<<256, 256, 0, stream>>>(mout_w, outp_w, WcT);
    gemm1_mfma<<<dim3(128, 8), 256, 0, stream>>>(Abf, Wt, xh, zsbuf);
    fused_cxd<<<NR / 32, 256, 0, stream>>>(xh, conv_w, conv_b, x_proj, dt_w, dt_b,
                                           xcg, dlt, Bc, Cc);
    scan_pass1<<<NB * NCH * 2, 256, 0, stream>>>(dlt, xcg, Bc, A_log, Parr, Harr);
    scan_pass2<<<128, 256, 0, stream>>>(Parr, Harr);
    scan_pass3<<<NB * NCH * 2, 256, 0, stream>>>(dlt, xcg, zsbuf, Bc, Cc, A_log, D_param,
                                                 Harr, yf16);
    gemm_out_mfma<<<NR / 64, 256, 0, stream>>>(WcT, yf16, outp_b, out);
}

// Round 5
// 300.272 us; speedup vs baseline: 3.1499x; 1.0386x over previous
//
#include <hip/hip_runtime.h>
#include <hip/hip_bf16.h>
#include <math.h>

#define LSEQ 4096
#define NR   16384   // B*L
#define NB   4
#define CHUNK 64
#define NCH  64

typedef short bf16x8 __attribute__((ext_vector_type(8)));
typedef float f32x4  __attribute__((ext_vector_type(4)));

typedef __attribute__((address_space(1))) const void gvoid_t;
typedef __attribute__((address_space(3))) void svoid_t;

__device__ __forceinline__ void gld_lds16(void* lds, const void* g) {
    __builtin_amdgcn_global_load_lds((gvoid_t*)g, (svoid_t*)lds, 16, 0, 0);
}

__device__ __forceinline__ unsigned short to_bf16(float f) {
    union { float f; unsigned u; } x; x.f = f;
    unsigned r = (x.u + 0x7fff + ((x.u >> 16) & 1)) >> 16;
    return (unsigned short)r;
}
__device__ __forceinline__ float bf2f(unsigned short u) {
    union { unsigned u; float f; } x; x.u = ((unsigned)u) << 16;
    return x.f;
}
__device__ __forceinline__ float softplus_f(float x) {
    return x > 20.f ? x : __logf(1.f + __expf(x));
}
__device__ __forceinline__ float silu_f(float x) {
    return x / (1.f + __expf(-x));
}

// ---------------- K1: fused rowstats + LN + transpose + bf16 cast ----------------
__global__ __launch_bounds__(256) void ln_fused(const float* __restrict__ in1,
                                                const float* __restrict__ in2,
                                                const float* __restrict__ g,
                                                const float* __restrict__ beta,
                                                unsigned short* __restrict__ Abf) {
    __shared__ float tile[256][33];
    __shared__ float s1[8][32], s2[8][32];
    __shared__ float smu[32], srs[32];
    int tid = threadIdx.x;
    int t0 = blockIdx.x * 32;
    int b  = blockIdx.y;
    #pragma unroll
    for (int p = 0; p < 8; ++p) {
        int c = p * 32 + (tid >> 3);
        int toff = (tid & 7) * 4;
        const float* src = (c < 128) ? &in1[((size_t)(b * 128 + c)) * LSEQ + t0 + toff]
                                     : &in2[((size_t)(b * 128 + (c - 128))) * LSEQ + t0 + toff];
        float4 v = *(const float4*)src;
        tile[c][toff] = v.x; tile[c][toff+1] = v.y;
        tile[c][toff+2] = v.z; tile[c][toff+3] = v.w;
    }
    __syncthreads();
    {
        int t = tid & 31, gg = tid >> 5;
        float a1 = 0.f, a2 = 0.f;
        #pragma unroll
        for (int i = 0; i < 32; ++i) {
            float v = tile[gg * 32 + i][t];
            a1 += v; a2 += v * v;
        }
        s1[gg][t] = a1; s2[gg][t] = a2;
    }
    __syncthreads();
    if (tid < 32) {
        float a1 = 0.f, a2 = 0.f;
        #pragma unroll
        for (int gg = 0; gg < 8; ++gg) { a1 += s1[gg][tid]; a2 += s2[gg][tid]; }
        float m = a1 * (1.f / 256.f);
        float var = a2 * (1.f / 256.f) - m * m;
        smu[tid] = m;
        srs[tid] = rsqrtf(var + 1e-5f);
    }
    __syncthreads();
    int c = tid;
    float gc = g[c], bc = beta[c];
    #pragma unroll 4
    for (int t = 0; t < 32; ++t) {
        float v = (tile[c][t] - smu[t]) * srs[t] * gc + bc;
        Abf[((size_t)((b << 12) + t0 + t)) * 256 + c] = to_bf16(v);
    }
}

// ---------------- K2: W[256][1024] -> Wt bf16 [1024][256] ----------------
__global__ __launch_bounds__(256) void wt_bf16_kernel(const float* __restrict__ W,
                                                      unsigned short* __restrict__ Wt) {
    __shared__ float tile[64][65];
    int k0 = blockIdx.x * 64;
    int n0 = blockIdx.y * 64;
    int tid = threadIdx.x;
    int a = tid & 63, q = tid >> 6;
    #pragma unroll
    for (int i = 0; i < 16; ++i) {
        int k = q * 16 + i;
        tile[k][a] = W[(size_t)(k0 + k) * 1024 + n0 + a];
    }
    __syncthreads();
    #pragma unroll
    for (int i = 0; i < 16; ++i) {
        int n = q * 16 + i;
        Wt[(size_t)(n0 + n) * 256 + k0 + a] = to_bf16(tile[a][n]);
    }
}

// ---------------- K3: WcT bf16 [128 c][512 k] = (Wm @ Wo)^T ----------------
__global__ __launch_bounds__(256) void wct_kernel(const float* __restrict__ Wm,
                                                  const float* __restrict__ Wo,
                                                  unsigned short* __restrict__ WcT) {
    int gid = blockIdx.x * 256 + threadIdx.x;   // 65536
    int row = gid >> 7, col = gid & 127;
    float acc = 0.f;
    for (int k = 0; k < 256; ++k) acc += Wm[row * 256 + k] * Wo[k * 128 + col];
    WcT[(size_t)col * 512 + row] = to_bf16(acc);
}

// ---------------- K3b: Wxp[512][48] -> Wxpt bf16 [48][512] ----------------
__global__ __launch_bounds__(256) void wxpt_kernel(const float* __restrict__ Wxp,
                                                   unsigned short* __restrict__ Wxpt) {
    int gid = blockIdx.x * 256 + threadIdx.x;   // 24576
    int n = gid >> 9, k = gid & 511;
    Wxpt[gid] = to_bf16(Wxp[(size_t)k * 48 + n]);
}

// ---------------- K4: MFMA in_proj GEMM, silu on z half, bf16 out ----------------
__global__ __launch_bounds__(256) void gemm1_mfma(const unsigned short* __restrict__ Abf,
                                                  const unsigned short* __restrict__ Wt,
                                                  unsigned short* __restrict__ xh,
                                                  unsigned short* __restrict__ zs) {
    __shared__ __align__(16) short Asl[128][32];
    __shared__ __align__(16) short Bsl[128][32];
    int tid = threadIdx.x;
    int wv = tid >> 6, ln = tid & 63;
    int m0 = blockIdx.x * 128;
    int n0 = blockIdx.y * 128;
    int mw = (wv & 1) * 64, nw = (wv >> 1) * 64;

    f32x4 acc[4][4];
    #pragma unroll
    for (int i = 0; i < 4; ++i)
        #pragma unroll
        for (int j = 0; j < 4; ++j) acc[i][j] = (f32x4)(0.f);

    int srow  = ln >> 2;
    int skoff = (ln & 3) * 8;

    for (int k0 = 0; k0 < 256; k0 += 32) {
        #pragma unroll
        for (int i = 0; i < 2; ++i) {
            int j = wv * 2 + i;
            int row = j * 16 + srow;
            gld_lds16(&Asl[j * 16][0], &Abf[(size_t)(m0 + row) * 256 + k0 + skoff]);
            gld_lds16(&Bsl[j * 16][0], &Wt [(size_t)(n0 + row) * 256 + k0 + skoff]);
        }
        __syncthreads();
        bf16x8 af[4], bff[4];
        int fm = ln & 15, fk = (ln >> 4) * 8;
        #pragma unroll
        for (int i = 0; i < 4; ++i) {
            af[i]  = *(const bf16x8*)&Asl[mw + i * 16 + fm][fk];
            bff[i] = *(const bf16x8*)&Bsl[nw + i * 16 + fm][fk];
        }
        #pragma unroll
        for (int i = 0; i < 4; ++i)
            #pragma unroll
            for (int j = 0; j < 4; ++j)
                acc[i][j] = __builtin_amdgcn_mfma_f32_16x16x32_bf16(af[i], bff[j], acc[i][j], 0, 0, 0);
        __syncthreads();
    }
    int ccol = ln & 15, crow = (ln >> 4) * 4;
    bool zhalf = (n0 >= 512);
    #pragma unroll
    for (int i = 0; i < 4; ++i) {
        #pragma unroll
        for (int j = 0; j < 4; ++j) {
            int n = n0 + nw + j * 16 + ccol;
            #pragma unroll
            for (int r = 0; r < 4; ++r) {
                int m = m0 + mw + i * 16 + crow + r;
                float v = acc[i][j][r];
                if (zhalf) zs[(size_t)m * 512 + (n - 512)] = to_bf16(silu_f(v));
                else       xh[(size_t)m * 512 + n]         = to_bf16(v);
            }
        }
    }
}

// ---------------- K5: conv(k=4) + SiLU, vectorized bf16x8 ----------------
// thread: 8 d at one t; block covers 4 t; grid (1024, NB)
__global__ __launch_bounds__(256) void conv_silu(const unsigned short* __restrict__ xh,
                                                 const float* __restrict__ cw,
                                                 const float* __restrict__ cb,
                                                 unsigned short* __restrict__ xcg) {
    int tid = threadIdx.x;
    int d0 = (tid & 63) * 8;
    int t  = blockIdx.x * 4 + (tid >> 6);
    int b  = blockIdx.y;
    float w[8][4], acc[8];
    #pragma unroll
    for (int i = 0; i < 8; ++i) {
        float4 w4 = *(const float4*)&cw[(d0 + i) * 4];
        w[i][0] = w4.x; w[i][1] = w4.y; w[i][2] = w4.z; w[i][3] = w4.w;
        acc[i] = cb[d0 + i];
    }
    #pragma unroll
    for (int k = 0; k < 4; ++k) {
        int tt = t - 3 + k;
        if (tt >= 0) {
            bf16x8 v = *(const bf16x8*)&xh[((size_t)((b << 12) + tt)) * 512 + d0];
            #pragma unroll
            for (int i = 0; i < 8; ++i)
                acc[i] += bf2f((unsigned short)v[i]) * w[i][k];
        }
    }
    bf16x8 outv;
    #pragma unroll
    for (int i = 0; i < 8; ++i) outv[i] = (short)to_bf16(silu_f(acc[i]));
    *(bf16x8*)&xcg[((size_t)((b << 12) + t)) * 512 + d0] = outv;
}

// ---------------- K6: MFMA xproj GEMM  xdbl[16384][48] = xc @ Wxp ----------------
// M-tile 128, N=48, K=512, BK=32; wave covers 32 rows (2 m-frags) x 48 cols (3 n-frags)
__global__ __launch_bounds__(256) void xproj_mfma(const unsigned short* __restrict__ xcg,
                                                  const unsigned short* __restrict__ Wxpt,
                                                  float* __restrict__ xdbl) {
    __shared__ __align__(16) short Xs[128][32];
    __shared__ __align__(16) short Ws[48][32];
    int tid = threadIdx.x;
    int wv = tid >> 6, ln = tid & 63;
    int m0 = blockIdx.x * 128;

    f32x4 acc[2][3];
    #pragma unroll
    for (int i = 0; i < 2; ++i)
        #pragma unroll
        for (int j = 0; j < 3; ++j) acc[i][j] = (f32x4)(0.f);

    for (int k0 = 0; k0 < 512; k0 += 32) {
        #pragma unroll
        for (int i = 0; i < 2; ++i) {
            int idx = (wv * 2 + i) * 64 + ln;      // 0..511
            int row = idx >> 2, c = idx & 3;
            gld_lds16(&Xs[0][0] + (size_t)idx * 8,
                      &xcg[(size_t)(m0 + row) * 512 + k0 + c * 8]);
        }
        if (wv < 3) {
            int idx = wv * 64 + ln;                // 0..191
            int row = idx >> 2, c = idx & 3;
            gld_lds16(&Ws[0][0] + (size_t)idx * 8,
                      &Wxpt[(size_t)row * 512 + k0 + c * 8]);
        }
        __syncthreads();
        bf16x8 af[2], bff[3];
        int fm = ln & 15, fk = (ln >> 4) * 8;
        #pragma unroll
        for (int i = 0; i < 2; ++i) af[i]  = *(const bf16x8*)&Xs[wv * 32 + i * 16 + fm][fk];
        #pragma unroll
        for (int j = 0; j < 3; ++j) bff[j] = *(const bf16x8*)&Ws[j * 16 + fm][fk];
        #pragma unroll
        for (int i = 0; i < 2; ++i)
            #pragma unroll
            for (int j = 0; j < 3; ++j)
                acc[i][j] = __builtin_amdgcn_mfma_f32_16x16x32_bf16(af[i], bff[j], acc[i][j], 0, 0, 0);
        __syncthreads();
    }
    int ccol = ln & 15, crow = (ln >> 4) * 4;
    #pragma unroll
    for (int i = 0; i < 2; ++i) {
        #pragma unroll
        for (int j = 0; j < 3; ++j) {
            #pragma unroll
            for (int r = 0; r < 4; ++r) {
                int m = m0 + wv * 32 + i * 16 + crow + r;
                xdbl[(size_t)m * 48 + j * 16 + ccol] = acc[i][j][r];
            }
        }
    }
}

// ---------------- K7: delta = softplus(dt @ Wdt + b), bf16 out ----------------
// 16 rows/block, 1024 blocks; thread handles 2 adjacent d
__global__ __launch_bounds__(256) void dt_kernel(const float* __restrict__ xdbl,
                                                 const float* __restrict__ Wdt,
                                                 const float* __restrict__ dtb,
                                                 unsigned short* __restrict__ deltag) {
    __shared__ float sdt[16][16];
    int tid = threadIdx.x;
    int r0 = blockIdx.x * 16;
    {
        int r = tid >> 4, q = tid & 15;
        sdt[r][q] = xdbl[(size_t)(r0 + r) * 48 + q];
    }
    __syncthreads();
    int d = tid * 2;
    float2 wv[16];
    #pragma unroll
    for (int q = 0; q < 16; ++q) wv[q] = *(const float2*)&Wdt[q * 512 + d];
    float b0 = dtb[d], b1 = dtb[d + 1];
    #pragma unroll 4
    for (int r = 0; r < 16; ++r) {
        float a0 = b0, a1 = b1;
        #pragma unroll
        for (int q = 0; q < 16; ++q) {
            float s = sdt[r][q];
            a0 += s * wv[q].x; a1 += s * wv[q].y;
        }
        unsigned u0 = to_bf16(softplus_f(a0));
        unsigned u1 = to_bf16(softplus_f(a1));
        *(unsigned*)&deltag[(size_t)(r0 + r) * 512 + d] = u0 | (u1 << 16);
    }
}

// ---------------- K8: scan pass 1 ----------------
__global__ __launch_bounds__(256) void scan_pass1(const unsigned short* __restrict__ deltag,
                                                  const unsigned short* __restrict__ xcg,
                                                  const float* __restrict__ xdbl,
                                                  const float* __restrict__ A_log,
                                                  float* __restrict__ Parr,
                                                  float* __restrict__ Harr) {
    __shared__ float sB[CHUNK][16];
    int tid = threadIdx.x;
    int chunk = blockIdx.x & (NCH - 1);
    int half  = (blockIdx.x >> 6) & 1;
    int b     = blockIdx.x >> 7;
    int d = half * 256 + tid;
    float Aneg[16];
    #pragma unroll
    for (int n = 0; n < 16; n += 4) {
        float4 v = *(const float4*)&A_log[d * 16 + n];
        Aneg[n] = -__expf(v.x); Aneg[n+1] = -__expf(v.y);
        Aneg[n+2] = -__expf(v.z); Aneg[n+3] = -__expf(v.w);
    }
    int rbase = (b << 12) + chunk * CHUNK;
    #pragma unroll
    for (int i = 0; i < 4; ++i) {
        int e = tid + i * 256;
        int t = e >> 4, n = e & 15;
        sB[t][n] = xdbl[(size_t)(rbase + t) * 48 + 16 + n];
    }
    __syncthreads();
    float h[16];
    float S = 0.f;
    #pragma unroll
    for (int n = 0; n < 16; ++n) h[n] = 0.f;
    #pragma unroll 4
    for (int t = 0; t < CHUNK; ++t) {
        float dv = bf2f(deltag[(size_t)(rbase + t) * 512 + d]);
        float xv = bf2f(xcg[(size_t)(rbase + t) * 512 + d]);
        float dx = dv * xv;
        S += dv;
        #pragma unroll
        for (int n = 0; n < 16; ++n) {
            float a = __expf(dv * Aneg[n]);
            h[n] = h[n] * a + dx * sB[t][n];
        }
    }
    size_t gbase = ((size_t)(b * 512 + d)) * 16;
    size_t coff  = (size_t)chunk * 32768;
    #pragma unroll
    for (int n = 0; n < 16; n += 4) {
        *(float4*)&Parr[coff + gbase + n] = make_float4(__expf(S * Aneg[n]), __expf(S * Aneg[n+1]),
                                                        __expf(S * Aneg[n+2]), __expf(S * Aneg[n+3]));
        *(float4*)&Harr[coff + gbase + n] = make_float4(h[n], h[n+1], h[n+2], h[n+3]);
    }
}

// ---------------- K9: scan pass 2 (carry across chunks) ----------------
__global__ __launch_bounds__(256) void scan_pass2(const float* __restrict__ Parr,
                                                  float* __restrict__ Harr) {
    int gid = blockIdx.x * 256 + threadIdx.x;   // 32768
    float carry = 0.f;
    #pragma unroll 8
    for (int c = 0; c < NCH; ++c) {
        size_t off = (size_t)c * 32768 + gid;
        float P = Parr[off], he = Harr[off];
        Harr[off] = carry;
        carry = he + P * carry;
    }
}

// ---------------- K10: scan pass 3 + D-skip + gating ----------------
__global__ __launch_bounds__(256) void scan_pass3(const unsigned short* __restrict__ deltag,
                                                  const unsigned short* __restrict__ xcg,
                                                  const unsigned short* __restrict__ zs,
                                                  const float* __restrict__ xdbl,
                                                  const float* __restrict__ A_log,
                                                  const float* __restrict__ Dp,
                                                  const float* __restrict__ Hin,
                                                  unsigned short* __restrict__ yf16) {
    __shared__ float2 sBC[CHUNK][16];
    int tid = threadIdx.x;
    int chunk = blockIdx.x & (NCH - 1);
    int half  = (blockIdx.x >> 6) & 1;
    int b     = blockIdx.x >> 7;
    int d = half * 256 + tid;
    float Aneg[16];
    #pragma unroll
    for (int n = 0; n < 16; n += 4) {
        float4 v = *(const float4*)&A_log[d * 16 + n];
        Aneg[n] = -__expf(v.x); Aneg[n+1] = -__expf(v.y);
        Aneg[n+2] = -__expf(v.z); Aneg[n+3] = -__expf(v.w);
    }
    float Dv = Dp[d];
    int rbase = (b << 12) + chunk * CHUNK;
    #pragma unroll
    for (int i = 0; i < 4; ++i) {
        int e = tid + i * 256;
        int t = e >> 4, n = e & 15;
        sBC[t][n] = make_float2(xdbl[(size_t)(rbase + t) * 48 + 16 + n],
                                xdbl[(size_t)(rbase + t) * 48 + 32 + n]);
    }
    __syncthreads();
    size_t gbase = ((size_t)(b * 512 + d)) * 16;
    size_t coff  = (size_t)chunk * 32768;
    float h[16];
    #pragma unroll
    for (int n = 0; n < 16; n += 4) {
        float4 v = *(const float4*)&Hin[coff + gbase + n];
        h[n] = v.x; h[n+1] = v.y; h[n+2] = v.z; h[n+3] = v.w;
    }
    #pragma unroll 4
    for (int t = 0; t < CHUNK; ++t) {
        float dv = bf2f(deltag[(size_t)(rbase + t) * 512 + d]);
        float xv = bf2f(xcg[(size_t)(rbase + t) * 512 + d]);
        float zv = bf2f(zs[(size_t)(rbase + t) * 512 + d]);
        float dx = dv * xv;
        float y = 0.f;
        #pragma unroll
        for (int n = 0; n < 16; ++n) {
            float2 bc = sBC[t][n];
            float a = __expf(dv * Aneg[n]);
            h[n] = h[n] * a + dx * bc.x;
            y += h[n] * bc.y;
        }
        y += xv * Dv;
        y *= zv;
        yf16[(size_t)(rbase + t) * 512 + d] = to_bf16(y);
    }
}

// ---------------- K11: MFMA out GEMM ----------------
__global__ __launch_bounds__(256) void gemm_out_mfma(const unsigned short* __restrict__ WcT,
                                                     const unsigned short* __restrict__ yf16,
                                                     const float* __restrict__ bo,
                                                     float* __restrict__ out) {
    __shared__ __align__(16) short Asl[128][32];
    __shared__ __align__(16) short Bsl[64][32];
    int tid = threadIdx.x;
    int wv = tid >> 6, ln = tid & 63;
    int n0 = blockIdx.x * 64;
    int mw = (wv & 1) * 64, nw = (wv >> 1) * 32;

    f32x4 acc[4][2];
    #pragma unroll
    for (int i = 0; i < 4; ++i)
        #pragma unroll
        for (int j = 0; j < 2; ++j) acc[i][j] = (f32x4)(0.f);

    int srow  = ln >> 2;
    int skoff = (ln & 3) * 8;

    for (int k0 = 0; k0 < 512; k0 += 32) {
        #pragma unroll
        for (int i = 0; i < 2; ++i) {
            int j = wv * 2 + i;
            int row = j * 16 + srow;
            gld_lds16(&Asl[j * 16][0], &WcT[(size_t)row * 512 + k0 + skoff]);
        }
        {
            int row = wv * 16 + srow;
            gld_lds16(&Bsl[wv * 16][0], &yf16[(size_t)(n0 + row) * 512 + k0 + skoff]);
        }
        __syncthreads();
        bf16x8 af[4], bff[2];
        int fm = ln & 15, fk = (ln >> 4) * 8;
        #pragma unroll
        for (int i = 0; i < 4; ++i) af[i]  = *(const bf16x8*)&Asl[mw + i * 16 + fm][fk];
        #pragma unroll
        for (int j = 0; j < 2; ++j) bff[j] = *(const bf16x8*)&Bsl[nw + j * 16 + fm][fk];
        #pragma unroll
        for (int i = 0; i < 4; ++i)
            #pragma unroll
            for (int j = 0; j < 2; ++j)
                acc[i][j] = __builtin_amdgcn_mfma_f32_16x16x32_bf16(af[i], bff[j], acc[i][j], 0, 0, 0);
        __syncthreads();
    }
    int ccol = ln & 15, crow = (ln >> 4) * 4;
    int b = n0 >> 12, tb = n0 & 4095;
    #pragma unroll
    for (int i = 0; i < 4; ++i) {
        #pragma unroll
        for (int r = 0; r < 4; ++r) {
            int c = mw + i * 16 + crow + r;
            float bias = bo[c];
            #pragma unroll
            for (int j = 0; j < 2; ++j) {
                int t = tb + nw + j * 16 + ccol;
                out[((size_t)(b * 128 + c)) * LSEQ + t] = acc[i][j][r] + bias;
            }
        }
    }
}

// ---------------- launch ----------------
extern "C" void kernel_launch(void* const* d_in, const int* in_sizes, int n_in,
                              void* d_out, int out_size, void* d_ws, size_t ws_size,
                              hipStream_t stream) {
    (void)in_sizes; (void)n_in; (void)out_size; (void)ws_size;
    const float* input    = (const float*)d_in[0];
    const float* input2   = (const float*)d_in[1];
    const float* ln_g     = (const float*)d_in[2];
    const float* ln_b     = (const float*)d_in[3];
    const float* outp_w   = (const float*)d_in[4];
    const float* outp_b   = (const float*)d_in[5];
    const float* in_proj  = (const float*)d_in[6];
    const float* conv_w   = (const float*)d_in[7];
    const float* conv_b   = (const float*)d_in[8];
    const float* x_proj   = (const float*)d_in[9];
    const float* dt_w     = (const float*)d_in[10];
    const float* dt_b     = (const float*)d_in[11];
    const float* A_log    = (const float*)d_in[12];
    const float* D_param  = (const float*)d_in[13];
    const float* mout_w   = (const float*)d_in[14];
    float* out = (float*)d_out;

    char* ws = (char*)d_ws;
    unsigned short* xh    = (unsigned short*)ws;                    ws += (size_t)NR * 512 * 2;
    unsigned short* zsbuf = (unsigned short*)ws;                    ws += (size_t)NR * 512 * 2;
    unsigned short* xcg   = (unsigned short*)ws;                    ws += (size_t)NR * 512 * 2;
    unsigned short* dlt   = (unsigned short*)ws;                    ws += (size_t)NR * 512 * 2;
    unsigned short* yf16  = (unsigned short*)ws;                    ws += (size_t)NR * 512 * 2;
    unsigned short* Abf   = (unsigned short*)ws;                    ws += (size_t)NR * 256 * 2;
    unsigned short* Wt    = (unsigned short*)ws;                    ws += (size_t)1024 * 256 * 2;
    unsigned short* WcT   = (unsigned short*)ws;                    ws += (size_t)128 * 512 * 2;
    unsigned short* Wxpt  = (unsigned short*)ws;                    ws += (size_t)48 * 512 * 2;
    float* xdbl = (float*)ws;                                       ws += (size_t)NR * 48 * 4;
    float* Parr = (float*)ws;                                       ws += (size_t)NCH * 32768 * 4;
    float* Harr = (float*)ws;                                       ws += (size_t)NCH * 32768 * 4;

    ln_fused<<<dim3(128, NB), 256, 0, stream>>>(input, input2, ln_g, ln_b, Abf);
    wt_bf16_kernel<<<dim3(4, 16), 256, 0, stream>>>(in_proj, Wt);
    wct_kernel<<<256, 256, 0, stream>>>(mout_w, outp_w, WcT);
    wxpt_kernel<<<96, 256, 0, stream>>>(x_proj, Wxpt);
    gemm1_mfma<<<dim3(128, 8), 256, 0, stream>>>(Abf, Wt, xh, zsbuf);
    conv_silu<<<dim3(1024, NB), 256, 0, stream>>>(xh, conv_w, conv_b, xcg);
    xproj_mfma<<<128, 256, 0, stream>>>(xcg, Wxpt, xdbl);
    dt_kernel<<<1024, 256, 0, stream>>>(xdbl, dt_w, dt_b, dlt);
    scan_pass1<<<NB * NCH * 2, 256, 0, stream>>>(dlt, xcg, xdbl, A_log, Parr, Harr);
    scan_pass2<<<128, 256, 0, stream>>>(Parr, Harr);
    scan_pass3<<<NB * NCH * 2, 256, 0, stream>>>(dlt, xcg, zsbuf, xdbl, A_log, D_param,
                                                 Harr, yf16);
    gemm_out_mfma<<<NR / 64, 256, 0, stream>>>(WcT, yf16, outp_b, out);
}

// Round 6
// 287.396 us; speedup vs baseline: 3.2910x; 1.0448x over previous
//
#include <hip/hip_runtime.h>
#include <hip/hip_bf16.h>
#include <math.h>

#define LSEQ 4096
#define NR   16384   // B*L
#define NB   4
#define CHUNK 32
#define NCH  128

typedef short bf16x8 __attribute__((ext_vector_type(8)));
typedef float f32x4  __attribute__((ext_vector_type(4)));

typedef __attribute__((address_space(1))) const void gvoid_t;
typedef __attribute__((address_space(3))) void svoid_t;

__device__ __forceinline__ void gld_lds16(void* lds, const void* g) {
    __builtin_amdgcn_global_load_lds((gvoid_t*)g, (svoid_t*)lds, 16, 0, 0);
}

__device__ __forceinline__ unsigned short to_bf16(float f) {
    union { float f; unsigned u; } x; x.f = f;
    unsigned r = (x.u + 0x7fff + ((x.u >> 16) & 1)) >> 16;
    return (unsigned short)r;
}
__device__ __forceinline__ float bf2f(unsigned short u) {
    union { unsigned u; float f; } x; x.u = ((unsigned)u) << 16;
    return x.f;
}
__device__ __forceinline__ float softplus_f(float x) {
    return x > 20.f ? x : __logf(1.f + __expf(x));
}
__device__ __forceinline__ float silu_f(float x) {
    return x / (1.f + __expf(-x));
}

// ---------------- K1: fused rowstats + LN + transpose + bf16 cast ----------------
__global__ __launch_bounds__(256) void ln_fused(const float* __restrict__ in1,
                                                const float* __restrict__ in2,
                                                const float* __restrict__ g,
                                                const float* __restrict__ beta,
                                                unsigned short* __restrict__ Abf) {
    __shared__ float tile[256][33];
    __shared__ float s1[8][32], s2[8][32];
    __shared__ float smu[32], srs[32];
    int tid = threadIdx.x;
    int t0 = blockIdx.x * 32;
    int b  = blockIdx.y;
    #pragma unroll
    for (int p = 0; p < 8; ++p) {
        int c = p * 32 + (tid >> 3);
        int toff = (tid & 7) * 4;
        const float* src = (c < 128) ? &in1[((size_t)(b * 128 + c)) * LSEQ + t0 + toff]
                                     : &in2[((size_t)(b * 128 + (c - 128))) * LSEQ + t0 + toff];
        float4 v = *(const float4*)src;
        tile[c][toff] = v.x; tile[c][toff+1] = v.y;
        tile[c][toff+2] = v.z; tile[c][toff+3] = v.w;
    }
    __syncthreads();
    {
        int t = tid & 31, gg = tid >> 5;
        float a1 = 0.f, a2 = 0.f;
        #pragma unroll
        for (int i = 0; i < 32; ++i) {
            float v = tile[gg * 32 + i][t];
            a1 += v; a2 += v * v;
        }
        s1[gg][t] = a1; s2[gg][t] = a2;
    }
    __syncthreads();
    if (tid < 32) {
        float a1 = 0.f, a2 = 0.f;
        #pragma unroll
        for (int gg = 0; gg < 8; ++gg) { a1 += s1[gg][tid]; a2 += s2[gg][tid]; }
        float m = a1 * (1.f / 256.f);
        float var = a2 * (1.f / 256.f) - m * m;
        smu[tid] = m;
        srs[tid] = rsqrtf(var + 1e-5f);
    }
    __syncthreads();
    int c = tid;
    float gc = g[c], bc = beta[c];
    #pragma unroll 4
    for (int t = 0; t < 32; ++t) {
        float v = (tile[c][t] - smu[t]) * srs[t] * gc + bc;
        Abf[((size_t)((b << 12) + t0 + t)) * 256 + c] = to_bf16(v);
    }
}

// ---------------- K2: W[256][1024] -> Wt bf16 [1024][256] ----------------
__global__ __launch_bounds__(256) void wt_bf16_kernel(const float* __restrict__ W,
                                                      unsigned short* __restrict__ Wt) {
    __shared__ float tile[64][65];
    int k0 = blockIdx.x * 64;
    int n0 = blockIdx.y * 64;
    int tid = threadIdx.x;
    int a = tid & 63, q = tid >> 6;
    #pragma unroll
    for (int i = 0; i < 16; ++i) {
        int k = q * 16 + i;
        tile[k][a] = W[(size_t)(k0 + k) * 1024 + n0 + a];
    }
    __syncthreads();
    #pragma unroll
    for (int i = 0; i < 16; ++i) {
        int n = q * 16 + i;
        Wt[(size_t)(n0 + n) * 256 + k0 + a] = to_bf16(tile[a][n]);
    }
}

// ---------------- K3: WcT bf16 [128 c][512 k] = (Wm @ Wo)^T ----------------
__global__ __launch_bounds__(256) void wct_kernel(const float* __restrict__ Wm,
                                                  const float* __restrict__ Wo,
                                                  unsigned short* __restrict__ WcT) {
    int gid = blockIdx.x * 256 + threadIdx.x;   // 65536
    int row = gid >> 7, col = gid & 127;
    float acc = 0.f;
    for (int k = 0; k < 256; ++k) acc += Wm[row * 256 + k] * Wo[k * 128 + col];
    WcT[(size_t)col * 512 + row] = to_bf16(acc);
}

// ---------------- K3b: Wxp[512][48] -> Wxpt bf16 [48][512] ----------------
__global__ __launch_bounds__(256) void wxpt_kernel(const float* __restrict__ Wxp,
                                                   unsigned short* __restrict__ Wxpt) {
    int gid = blockIdx.x * 256 + threadIdx.x;   // 24576
    int n = gid >> 9, k = gid & 511;
    Wxpt[gid] = to_bf16(Wxp[(size_t)k * 48 + n]);
}

// ---------------- K4: MFMA in_proj GEMM, silu on z half, bf16 out ----------------
__global__ __launch_bounds__(256) void gemm1_mfma(const unsigned short* __restrict__ Abf,
                                                  const unsigned short* __restrict__ Wt,
                                                  unsigned short* __restrict__ xh,
                                                  unsigned short* __restrict__ zs) {
    __shared__ __align__(16) short Asl[128][32];
    __shared__ __align__(16) short Bsl[128][32];
    int tid = threadIdx.x;
    int wv = tid >> 6, ln = tid & 63;
    int m0 = blockIdx.x * 128;
    int n0 = blockIdx.y * 128;
    int mw = (wv & 1) * 64, nw = (wv >> 1) * 64;

    f32x4 acc[4][4];
    #pragma unroll
    for (int i = 0; i < 4; ++i)
        #pragma unroll
        for (int j = 0; j < 4; ++j) acc[i][j] = (f32x4)(0.f);

    int srow  = ln >> 2;
    int skoff = (ln & 3) * 8;

    for (int k0 = 0; k0 < 256; k0 += 32) {
        #pragma unroll
        for (int i = 0; i < 2; ++i) {
            int j = wv * 2 + i;
            int row = j * 16 + srow;
            gld_lds16(&Asl[j * 16][0], &Abf[(size_t)(m0 + row) * 256 + k0 + skoff]);
            gld_lds16(&Bsl[j * 16][0], &Wt [(size_t)(n0 + row) * 256 + k0 + skoff]);
        }
        __syncthreads();
        bf16x8 af[4], bff[4];
        int fm = ln & 15, fk = (ln >> 4) * 8;
        #pragma unroll
        for (int i = 0; i < 4; ++i) {
            af[i]  = *(const bf16x8*)&Asl[mw + i * 16 + fm][fk];
            bff[i] = *(const bf16x8*)&Bsl[nw + i * 16 + fm][fk];
        }
        #pragma unroll
        for (int i = 0; i < 4; ++i)
            #pragma unroll
            for (int j = 0; j < 4; ++j)
                acc[i][j] = __builtin_amdgcn_mfma_f32_16x16x32_bf16(af[i], bff[j], acc[i][j], 0, 0, 0);
        __syncthreads();
    }
    int ccol = ln & 15, crow = (ln >> 4) * 4;
    bool zhalf = (n0 >= 512);
    #pragma unroll
    for (int i = 0; i < 4; ++i) {
        #pragma unroll
        for (int j = 0; j < 4; ++j) {
            int n = n0 + nw + j * 16 + ccol;
            #pragma unroll
            for (int r = 0; r < 4; ++r) {
                int m = m0 + mw + i * 16 + crow + r;
                float v = acc[i][j][r];
                if (zhalf) zs[(size_t)m * 512 + (n - 512)] = to_bf16(silu_f(v));
                else       xh[(size_t)m * 512 + n]         = to_bf16(v);
            }
        }
    }
}

// ---------------- K5: conv(k=4) + SiLU, vectorized bf16x8 ----------------
__global__ __launch_bounds__(256) void conv_silu(const unsigned short* __restrict__ xh,
                                                 const float* __restrict__ cw,
                                                 const float* __restrict__ cb,
                                                 unsigned short* __restrict__ xcg) {
    int tid = threadIdx.x;
    int d0 = (tid & 63) * 8;
    int t  = blockIdx.x * 4 + (tid >> 6);
    int b  = blockIdx.y;
    float w[8][4], acc[8];
    #pragma unroll
    for (int i = 0; i < 8; ++i) {
        float4 w4 = *(const float4*)&cw[(d0 + i) * 4];
        w[i][0] = w4.x; w[i][1] = w4.y; w[i][2] = w4.z; w[i][3] = w4.w;
        acc[i] = cb[d0 + i];
    }
    #pragma unroll
    for (int k = 0; k < 4; ++k) {
        int tt = t - 3 + k;
        if (tt >= 0) {
            bf16x8 v = *(const bf16x8*)&xh[((size_t)((b << 12) + tt)) * 512 + d0];
            #pragma unroll
            for (int i = 0; i < 8; ++i)
                acc[i] += bf2f((unsigned short)v[i]) * w[i][k];
        }
    }
    bf16x8 outv;
    #pragma unroll
    for (int i = 0; i < 8; ++i) outv[i] = (short)to_bf16(silu_f(acc[i]));
    *(bf16x8*)&xcg[((size_t)((b << 12) + t)) * 512 + d0] = outv;
}

// ---------------- K6: MFMA xproj GEMM  xdbl[16384][48] = xc @ Wxp ----------------
__global__ __launch_bounds__(256) void xproj_mfma(const unsigned short* __restrict__ xcg,
                                                  const unsigned short* __restrict__ Wxpt,
                                                  float* __restrict__ xdbl) {
    __shared__ __align__(16) short Xs[128][32];
    __shared__ __align__(16) short Ws[48][32];
    int tid = threadIdx.x;
    int wv = tid >> 6, ln = tid & 63;
    int m0 = blockIdx.x * 128;

    f32x4 acc[2][3];
    #pragma unroll
    for (int i = 0; i < 2; ++i)
        #pragma unroll
        for (int j = 0; j < 3; ++j) acc[i][j] = (f32x4)(0.f);

    for (int k0 = 0; k0 < 512; k0 += 32) {
        #pragma unroll
        for (int i = 0; i < 2; ++i) {
            int idx = (wv * 2 + i) * 64 + ln;
            int row = idx >> 2, c = idx & 3;
            gld_lds16(&Xs[0][0] + (size_t)idx * 8,
                      &xcg[(size_t)(m0 + row) * 512 + k0 + c * 8]);
        }
        if (wv < 3) {
            int idx = wv * 64 + ln;
            int row = idx >> 2, c = idx & 3;
            gld_lds16(&Ws[0][0] + (size_t)idx * 8,
                      &Wxpt[(size_t)row * 512 + k0 + c * 8]);
        }
        __syncthreads();
        bf16x8 af[2], bff[3];
        int fm = ln & 15, fk = (ln >> 4) * 8;
        #pragma unroll
        for (int i = 0; i < 2; ++i) af[i]  = *(const bf16x8*)&Xs[wv * 32 + i * 16 + fm][fk];
        #pragma unroll
        for (int j = 0; j < 3; ++j) bff[j] = *(const bf16x8*)&Ws[j * 16 + fm][fk];
        #pragma unroll
        for (int i = 0; i < 2; ++i)
            #pragma unroll
            for (int j = 0; j < 3; ++j)
                acc[i][j] = __builtin_amdgcn_mfma_f32_16x16x32_bf16(af[i], bff[j], acc[i][j], 0, 0, 0);
        __syncthreads();
    }
    int ccol = ln & 15, crow = (ln >> 4) * 4;
    #pragma unroll
    for (int i = 0; i < 2; ++i) {
        #pragma unroll
        for (int j = 0; j < 3; ++j) {
            #pragma unroll
            for (int r = 0; r < 4; ++r) {
                int m = m0 + wv * 32 + i * 16 + crow + r;
                xdbl[(size_t)m * 48 + j * 16 + ccol] = acc[i][j][r];
            }
        }
    }
}

// ---------------- K7: dt + pack (delta | xc) into one uint per (t,d) ----------------
// 16 rows/block, 1024 blocks; thread handles 2 adjacent d
__global__ __launch_bounds__(256) void dt_kernel(const float* __restrict__ xdbl,
                                                 const float* __restrict__ Wdt,
                                                 const float* __restrict__ dtb,
                                                 const unsigned short* __restrict__ xcg,
                                                 unsigned* __restrict__ dxp) {
    __shared__ float sdt[16][16];
    int tid = threadIdx.x;
    int r0 = blockIdx.x * 16;
    {
        int r = tid >> 4, q = tid & 15;
        sdt[r][q] = xdbl[(size_t)(r0 + r) * 48 + q];
    }
    __syncthreads();
    int d = tid * 2;
    float2 wv[16];
    #pragma unroll
    for (int q = 0; q < 16; ++q) wv[q] = *(const float2*)&Wdt[q * 512 + d];
    float b0 = dtb[d], b1 = dtb[d + 1];
    #pragma unroll 4
    for (int r = 0; r < 16; ++r) {
        float a0 = b0, a1 = b1;
        #pragma unroll
        for (int q = 0; q < 16; ++q) {
            float s = sdt[r][q];
            a0 += s * wv[q].x; a1 += s * wv[q].y;
        }
        unsigned xc2 = *(const unsigned*)&xcg[(size_t)(r0 + r) * 512 + d];
        unsigned u0 = (unsigned)to_bf16(softplus_f(a0)) | ((xc2 & 0xffffu) << 16);
        unsigned u1 = (unsigned)to_bf16(softplus_f(a1)) | (xc2 & 0xffff0000u);
        uint2 pk = make_uint2(u0, u1);
        *(uint2*)&dxp[(size_t)(r0 + r) * 512 + d] = pk;
    }
}

// ---------------- K8: scan pass 1 ----------------
__global__ __launch_bounds__(256) void scan_pass1(const unsigned* __restrict__ dxp,
                                                  const float* __restrict__ xdbl,
                                                  const float* __restrict__ A_log,
                                                  float* __restrict__ Parr,
                                                  float* __restrict__ Harr) {
    __shared__ float sB[CHUNK][16];
    int tid = threadIdx.x;
    int chunk = blockIdx.x & (NCH - 1);
    int half  = (blockIdx.x >> 7) & 1;
    int b     = blockIdx.x >> 8;
    int d = half * 256 + tid;
    float Aneg[16];
    #pragma unroll
    for (int n = 0; n < 16; n += 4) {
        float4 v = *(const float4*)&A_log[d * 16 + n];
        Aneg[n] = -__expf(v.x); Aneg[n+1] = -__expf(v.y);
        Aneg[n+2] = -__expf(v.z); Aneg[n+3] = -__expf(v.w);
    }
    int rbase = (b << 12) + chunk * CHUNK;
    #pragma unroll
    for (int i = 0; i < CHUNK * 16 / 256; ++i) {
        int e = tid + i * 256;
        int t = e >> 4, n = e & 15;
        sB[t][n] = xdbl[(size_t)(rbase + t) * 48 + 16 + n];
    }
    __syncthreads();
    float h[16];
    float S = 0.f;
    #pragma unroll
    for (int n = 0; n < 16; ++n) h[n] = 0.f;
    #pragma unroll 4
    for (int t = 0; t < CHUNK; ++t) {
        unsigned pw = dxp[(size_t)(rbase + t) * 512 + d];
        float dv = bf2f((unsigned short)(pw & 0xffffu));
        float xv = bf2f((unsigned short)(pw >> 16));
        float dx = dv * xv;
        S += dv;
        #pragma unroll
        for (int n = 0; n < 16; ++n) {
            float a = __expf(dv * Aneg[n]);
            h[n] = h[n] * a + dx * sB[t][n];
        }
    }
    size_t gbase = ((size_t)(b * 512 + d)) * 16;
    size_t coff  = (size_t)chunk * 32768;
    #pragma unroll
    for (int n = 0; n < 16; n += 4) {
        *(float4*)&Parr[coff + gbase + n] = make_float4(__expf(S * Aneg[n]), __expf(S * Aneg[n+1]),
                                                        __expf(S * Aneg[n+2]), __expf(S * Aneg[n+3]));
        *(float4*)&Harr[coff + gbase + n] = make_float4(h[n], h[n+1], h[n+2], h[n+3]);
    }
}

// ---------------- K9: scan pass 2 (carry across chunks) ----------------
__global__ __launch_bounds__(256) void scan_pass2(const float* __restrict__ Parr,
                                                  float* __restrict__ Harr) {
    int gid = blockIdx.x * 256 + threadIdx.x;   // 32768
    float carry = 0.f;
    #pragma unroll 8
    for (int c = 0; c < NCH; ++c) {
        size_t off = (size_t)c * 32768 + gid;
        float P = Parr[off], he = Harr[off];
        Harr[off] = carry;
        carry = he + P * carry;
    }
}

// ---------------- K10: scan pass 3 + D-skip + gating ----------------
__global__ __launch_bounds__(256) void scan_pass3(const unsigned* __restrict__ dxp,
                                                  const unsigned short* __restrict__ zs,
                                                  const float* __restrict__ xdbl,
                                                  const float* __restrict__ A_log,
                                                  const float* __restrict__ Dp,
                                                  const float* __restrict__ Hin,
                                                  unsigned short* __restrict__ yf16) {
    __shared__ float2 sBC[CHUNK][16];
    int tid = threadIdx.x;
    int chunk = blockIdx.x & (NCH - 1);
    int half  = (blockIdx.x >> 7) & 1;
    int b     = blockIdx.x >> 8;
    int d = half * 256 + tid;
    float Aneg[16];
    #pragma unroll
    for (int n = 0; n < 16; n += 4) {
        float4 v = *(const float4*)&A_log[d * 16 + n];
        Aneg[n] = -__expf(v.x); Aneg[n+1] = -__expf(v.y);
        Aneg[n+2] = -__expf(v.z); Aneg[n+3] = -__expf(v.w);
    }
    float Dv = Dp[d];
    int rbase = (b << 12) + chunk * CHUNK;
    #pragma unroll
    for (int i = 0; i < CHUNK * 16 / 256; ++i) {
        int e = tid + i * 256;
        int t = e >> 4, n = e & 15;
        sBC[t][n] = make_float2(xdbl[(size_t)(rbase + t) * 48 + 16 + n],
                                xdbl[(size_t)(rbase + t) * 48 + 32 + n]);
    }
    __syncthreads();
    size_t gbase = ((size_t)(b * 512 + d)) * 16;
    size_t coff  = (size_t)chunk * 32768;
    float h[16];
    #pragma unroll
    for (int n = 0; n < 16; n += 4) {
        float4 v = *(const float4*)&Hin[coff + gbase + n];
        h[n] = v.x; h[n+1] = v.y; h[n+2] = v.z; h[n+3] = v.w;
    }
    #pragma unroll 4
    for (int t = 0; t < CHUNK; ++t) {
        unsigned pw = dxp[(size_t)(rbase + t) * 512 + d];
        float dv = bf2f((unsigned short)(pw & 0xffffu));
        float xv = bf2f((unsigned short)(pw >> 16));
        float zv = bf2f(zs[(size_t)(rbase + t) * 512 + d]);
        float dx = dv * xv;
        float y = 0.f;
        #pragma unroll
        for (int n = 0; n < 16; ++n) {
            float2 bc = sBC[t][n];
            float a = __expf(dv * Aneg[n]);
            h[n] = h[n] * a + dx * bc.x;
            y += h[n] * bc.y;
        }
        y += xv * Dv;
        y *= zv;
        yf16[(size_t)(rbase + t) * 512 + d] = to_bf16(y);
    }
}

// ---------------- K11: MFMA out GEMM ----------------
__global__ __launch_bounds__(256) void gemm_out_mfma(const unsigned short* __restrict__ WcT,
                                                     const unsigned short* __restrict__ yf16,
                                                     const float* __restrict__ bo,
                                                     float* __restrict__ out) {
    __shared__ __align__(16) short Asl[128][32];
    __shared__ __align__(16) short Bsl[64][32];
    int tid = threadIdx.x;
    int wv = tid >> 6, ln = tid & 63;
    int n0 = blockIdx.x * 64;
    int mw = (wv & 1) * 64, nw = (wv >> 1) * 32;

    f32x4 acc[4][2];
    #pragma unroll
    for (int i = 0; i < 4; ++i)
        #pragma unroll
        for (int j = 0; j < 2; ++j) acc[i][j] = (f32x4)(0.f);

    int srow  = ln >> 2;
    int skoff = (ln & 3) * 8;

    for (int k0 = 0; k0 < 512; k0 += 32) {
        #pragma unroll
        for (int i = 0; i < 2; ++i) {
            int j = wv * 2 + i;
            int row = j * 16 + srow;
            gld_lds16(&Asl[j * 16][0], &WcT[(size_t)row * 512 + k0 + skoff]);
        }
        {
            int row = wv * 16 + srow;
            gld_lds16(&Bsl[wv * 16][0], &yf16[(size_t)(n0 + row) * 512 + k0 + skoff]);
        }
        __syncthreads();
        bf16x8 af[4], bff[2];
        int fm = ln & 15, fk = (ln >> 4) * 8;
        #pragma unroll
        for (int i = 0; i < 4; ++i) af[i]  = *(const bf16x8*)&Asl[mw + i * 16 + fm][fk];
        #pragma unroll
        for (int j = 0; j < 2; ++j) bff[j] = *(const bf16x8*)&Bsl[nw + j * 16 + fm][fk];
        #pragma unroll
        for (int i = 0; i < 4; ++i)
            #pragma unroll
            for (int j = 0; j < 2; ++j)
                acc[i][j] = __builtin_amdgcn_mfma_f32_16x16x32_bf16(af[i], bff[j], acc[i][j], 0, 0, 0);
        __syncthreads();
    }
    int ccol = ln & 15, crow = (ln >> 4) * 4;
    int b = n0 >> 12, tb = n0 & 4095;
    #pragma unroll
    for (int i = 0; i < 4; ++i) {
        #pragma unroll
        for (int r = 0; r < 4; ++r) {
            int c = mw + i * 16 + crow + r;
            float bias = bo[c];
            #pragma unroll
            for (int j = 0; j < 2; ++j) {
                int t = tb + nw + j * 16 + ccol;
                out[((size_t)(b * 128 + c)) * LSEQ + t] = acc[i][j][r] + bias;
            }
        }
    }
}

// ---------------- launch ----------------
extern "C" void kernel_launch(void* const* d_in, const int* in_sizes, int n_in,
                              void* d_out, int out_size, void* d_ws, size_t ws_size,
                              hipStream_t stream) {
    (void)in_sizes; (void)n_in; (void)out_size; (void)ws_size;
    const float* input    = (const float*)d_in[0];
    const float* input2   = (const float*)d_in[1];
    const float* ln_g     = (const float*)d_in[2];
    const float* ln_b     = (const float*)d_in[3];
    const float* outp_w   = (const float*)d_in[4];
    const float* outp_b   = (const float*)d_in[5];
    const float* in_proj  = (const float*)d_in[6];
    const float* conv_w   = (const float*)d_in[7];
    const float* conv_b   = (const float*)d_in[8];
    const float* x_proj   = (const float*)d_in[9];
    const float* dt_w     = (const float*)d_in[10];
    const float* dt_b     = (const float*)d_in[11];
    const float* A_log    = (const float*)d_in[12];
    const float* D_param  = (const float*)d_in[13];
    const float* mout_w   = (const float*)d_in[14];
    float* out = (float*)d_out;

    char* ws = (char*)d_ws;
    unsigned short* xh    = (unsigned short*)ws;                    ws += (size_t)NR * 512 * 2;
    unsigned short* zsbuf = (unsigned short*)ws;                    ws += (size_t)NR * 512 * 2;
    unsigned short* xcg   = (unsigned short*)ws;                    ws += (size_t)NR * 512 * 2;
    unsigned short* yf16  = (unsigned short*)ws;                    ws += (size_t)NR * 512 * 2;
    unsigned*       dxp   = (unsigned*)ws;                          ws += (size_t)NR * 512 * 4;
    unsigned short* Abf   = (unsigned short*)ws;                    ws += (size_t)NR * 256 * 2;
    unsigned short* Wt    = (unsigned short*)ws;                    ws += (size_t)1024 * 256 * 2;
    unsigned short* WcT   = (unsigned short*)ws;                    ws += (size_t)128 * 512 * 2;
    unsigned short* Wxpt  = (unsigned short*)ws;                    ws += (size_t)48 * 512 * 2;
    float* xdbl = (float*)ws;                                       ws += (size_t)NR * 48 * 4;
    float* Parr = (float*)ws;                                       ws += (size_t)NCH * 32768 * 4;
    float* Harr = (float*)ws;                                       ws += (size_t)NCH * 32768 * 4;

    ln_fused<<<dim3(128, NB), 256, 0, stream>>>(input, input2, ln_g, ln_b, Abf);
    wt_bf16_kernel<<<dim3(4, 16), 256, 0, stream>>>(in_proj, Wt);
    wct_kernel<<<256, 256, 0, stream>>>(mout_w, outp_w, WcT);
    wxpt_kernel<<<96, 256, 0, stream>>>(x_proj, Wxpt);
    gemm1_mfma<<<dim3(128, 8), 256, 0, stream>>>(Abf, Wt, xh, zsbuf);
    conv_silu<<<dim3(1024, NB), 256, 0, stream>>>(xh, conv_w, conv_b, xcg);
    xproj_mfma<<<128, 256, 0, stream>>>(xcg, Wxpt, xdbl);
    dt_kernel<<<1024, 256, 0, stream>>>(xdbl, dt_w, dt_b, xcg, dxp);
    scan_pass1<<<NB * NCH * 2, 256, 0, stream>>>(dxp, xdbl, A_log, Parr, Harr);
    scan_pass2<<<128, 256, 0, stream>>>(Parr, Harr);
    scan_pass3<<<NB * NCH * 2, 256, 0, stream>>>(dxp, zsbuf, xdbl, A_log, D_param,
                                                 Harr, yf16);
    gemm_out_mfma<<<NR / 64, 256, 0, stream>>>(WcT, yf16, outp_b, out);
}